// Round 2
// baseline (2726.388 us; speedup 1.0000x reference)
//
#include <hip/hip_runtime.h>
#include <cstddef>
#include <cstdint>
#include <type_traits>

// ---------------- problem constants ----------------
constexpr int DM = 1024;      // D_MODEL
constexpr int DI = 2048;      // D_INNER
constexpr int DS = 16;        // D_STATE
constexpr int NH = 8;         // NHEADS
constexpr int CD = 2080;      // CONV_DIM
constexpr int DP = 4136;      // D_IN_PROJ
constexpr int Q  = 64;        // CHUNK
constexpr int B_ = 4;         // BATCH
constexpr int L_ = 4096;      // SEQLEN
constexpr int NCH = 64;       // chunks per sequence
constexpr int HP = 256;       // HEADDIM
constexpr int NR = B_ * L_;   // 16384 rows

// ---------------- workspace layout (BYTE offsets, total ~228.3 MB) ----------------
constexpr size_t AL(size_t x) { return (x + 255) & ~(size_t)255; }
constexpr size_t OFFB_ZX = 0;                                   // zxbcdt bf16 (NR x DP)
constexpr size_t OFFB_BC = AL(OFFB_ZX + (size_t)NR * DP * 2);   // conv'd B,C fp32 (NR x 32)
constexpr size_t OFFB_DT = AL(OFFB_BC + (size_t)NR * 32 * 4);   // dt fp32 (NR x NH)
constexpr size_t OFFB_CS = AL(OFFB_DT + (size_t)NR * NH * 4);   // cumsum fp32 (B,NCH,NH,Q)
constexpr size_t OFFB_ST = AL(OFFB_CS + (size_t)B_ * NCH * NH * Q * 4); // states fp32 (B,NCH,NH,HP,DS)
constexpr size_t OFFB_Y  = AL(OFFB_ST + (size_t)B_ * NCH * NH * HP * DS * 4); // y bf16 (NR x DI)
// end = OFFB_Y + NR*DI*2  ~= 239.3 MB

__device__ __forceinline__ float silu_f(float x) { return x / (1.f + expf(-x)); }
__device__ __forceinline__ float bf2f(unsigned short v) {
  unsigned int u = ((unsigned int)v) << 16;
  return __builtin_bit_cast(float, u);
}
__device__ __forceinline__ unsigned short f2bf(float f) {
  unsigned int u = __builtin_bit_cast(unsigned int, f);
  u += 0x7FFFu + ((u >> 16) & 1u);   // round-to-nearest-even
  return (unsigned short)(u >> 16);
}

// ---------------- tiled GEMM: C[M,N] = A[M,K] @ B[K,N] ----------------
// TA in {float, unsigned short(bf16)}, B fp32, TC in {float, unsigned short(bf16)}.
// BM=BN=128, BK=16, 256 threads, 8x8 micro-tile as 2x2 quadrants of 4x4.
// M % 128 == 0, K % 16 == 0 assumed (true at all call sites); N guarded.
template<typename TA, typename TC>
__global__ __launch_bounds__(256)
void gemm_k(const TA* __restrict__ A, const float* __restrict__ B,
            TC* __restrict__ C, int M, int N, int K) {
  constexpr int BM = 128, BN = 128, BK = 16;
  __shared__ __align__(16) float As[BK][BM + 4];
  __shared__ __align__(16) float Bs[BK][BN + 4];
  const int t = threadIdx.x;
  const int bn = blockIdx.x, bm = blockIdx.y;
  const int row0 = bm * BM, col0 = bn * BN;
  const int tm = t >> 4, tn = t & 15;
  float acc[2][2][4][4] = {};

  for (int k0 = 0; k0 < K; k0 += BK) {
    // ---- A tile (BM x BK) -> As[k][m] transposed ----
    if constexpr (std::is_same<TA, float>::value) {
      #pragma unroll
      for (int r = 0; r < 2; ++r) {
        int f = t + r * 256;
        int m = f >> 2, k4 = (f & 3) << 2;
        float4 av = *(const float4*)(A + (size_t)(row0 + m) * K + (k0 + k4));
        As[k4 + 0][m] = av.x; As[k4 + 1][m] = av.y;
        As[k4 + 2][m] = av.z; As[k4 + 3][m] = av.w;
      }
    } else {  // bf16: one 16B load of 8 elems per thread
      int m = t >> 1, k8 = (t & 1) << 3;
      uint4 av = *(const uint4*)(A + (size_t)(row0 + m) * K + (k0 + k8));
      const unsigned short* sp = (const unsigned short*)&av;
      #pragma unroll
      for (int j = 0; j < 8; ++j) As[k8 + j][m] = bf2f(sp[j]);
    }
    // ---- B tile (BK x BN), N-guarded ----
    #pragma unroll
    for (int r = 0; r < 2; ++r) {
      int f = t + r * 256;
      int kk = f >> 5, c4 = (f & 31) << 2;
      int col = col0 + c4;
      float4 bv;
      if (col + 3 < N) {
        bv = *(const float4*)(B + (size_t)(k0 + kk) * N + col);
      } else {
        bv.x = (col + 0 < N) ? B[(size_t)(k0 + kk) * N + col + 0] : 0.f;
        bv.y = (col + 1 < N) ? B[(size_t)(k0 + kk) * N + col + 1] : 0.f;
        bv.z = (col + 2 < N) ? B[(size_t)(k0 + kk) * N + col + 2] : 0.f;
        bv.w = (col + 3 < N) ? B[(size_t)(k0 + kk) * N + col + 3] : 0.f;
      }
      *(float4*)&Bs[kk][c4] = bv;
    }
    __syncthreads();
    #pragma unroll
    for (int kk = 0; kk < BK; ++kk) {
      float am[2][4], bb[2][4];
      *(float4*)am[0] = *(const float4*)&As[kk][tm * 4];
      *(float4*)am[1] = *(const float4*)&As[kk][tm * 4 + 64];
      *(float4*)bb[0] = *(const float4*)&Bs[kk][tn * 4];
      *(float4*)bb[1] = *(const float4*)&Bs[kk][tn * 4 + 64];
      #pragma unroll
      for (int mi = 0; mi < 2; ++mi)
        #pragma unroll
        for (int ni = 0; ni < 2; ++ni)
          #pragma unroll
          for (int i = 0; i < 4; ++i)
            #pragma unroll
            for (int j = 0; j < 4; ++j)
              acc[mi][ni][i][j] += am[mi][i] * bb[ni][j];
    }
    __syncthreads();
  }
  #pragma unroll
  for (int mi = 0; mi < 2; ++mi)
    #pragma unroll
    for (int i = 0; i < 4; ++i) {
      const size_t row = row0 + mi * 64 + tm * 4 + i;
      #pragma unroll
      for (int ni = 0; ni < 2; ++ni) {
        const int col = col0 + ni * 64 + tn * 4;
        if constexpr (std::is_same<TC, float>::value) {
          if (col + 3 < N) {
            *(float4*)(C + row * (size_t)N + col) =
                make_float4(acc[mi][ni][i][0], acc[mi][ni][i][1],
                            acc[mi][ni][i][2], acc[mi][ni][i][3]);
          } else {
            for (int j = 0; j < 4; ++j)
              if (col + j < N) C[row * (size_t)N + col + j] = acc[mi][ni][i][j];
          }
        } else {
          if (col + 3 < N) {
            ushort4 o;
            o.x = f2bf(acc[mi][ni][i][0]); o.y = f2bf(acc[mi][ni][i][1]);
            o.z = f2bf(acc[mi][ni][i][2]); o.w = f2bf(acc[mi][ni][i][3]);
            *(ushort4*)(C + row * (size_t)N + col) = o;
          } else {
            for (int j = 0; j < 4; ++j)
              if (col + j < N) C[row * (size_t)N + col + j] = f2bf(acc[mi][ni][i][j]);
          }
        }
      }
    }
}

// ---------------- conv+SiLU for the 32 B/C channels only ----------------
// bc[l][0..15]=B, bc[l][16..31]=C (fp32). x-channels are convolved on the fly in chunk_kernel.
__global__ __launch_bounds__(256)
void convbc_kernel(const unsigned short* __restrict__ zx, const float* __restrict__ cw,
                   const float* __restrict__ cb, float* __restrict__ bc) {
  const int idx = blockIdx.x * 256 + threadIdx.x;   // < NR*32
  const int j = idx & 31;
  const int row = idx >> 5;
  const int l = row & (L_ - 1);
  const int cc = DI + j;                            // xBC channel 2048+j
  float a = cb[cc];
  #pragma unroll
  for (int k = 0; k < 4; ++k) {
    int ll = l - 3 + k;
    if (ll >= 0)
      a += bf2f(zx[(size_t)(row - 3 + k) * DP + (DI + DI + j)]) * cw[cc * 4 + k];
  }
  bc[(size_t)row * 32 + j] = silu_f(a);
}

// ---------------- dt = softplus(raw + bias) ----------------
__global__ __launch_bounds__(256)
void dt_kernel(const unsigned short* __restrict__ zx, const float* __restrict__ dt_bias,
               float* __restrict__ dt) {
  const int i = blockIdx.x * 256 + threadIdx.x;   // < NR*NH
  const int h = i & 7;
  const size_t row = (size_t)(i >> 3);
  float x = bf2f(zx[row * DP + (DI + CD) + h]) + dt_bias[h];
  dt[i] = (x > 20.f) ? x : log1pf(expf(x));
}

// ---------------- per-(b,chunk,head): cumsum + on-the-fly x-conv + Y_diag(+Dx) + states ----------------
__global__ __launch_bounds__(256)
void chunk_kernel(const unsigned short* __restrict__ zx, const float* __restrict__ bc,
                  const float* __restrict__ dt, const float* __restrict__ A_log,
                  const float* __restrict__ cw, const float* __restrict__ cb,
                  const float* __restrict__ Dp, float* __restrict__ cs_out,
                  float* __restrict__ states, unsigned short* __restrict__ yb) {
  const int c = blockIdx.x, h = blockIdx.y, b = blockIdx.z;
  const int t = threadIdx.x;
  __shared__ float dtS[Q], csS[Q], ddS[Q];
  __shared__ __align__(16) float BsS[Q][DS], CsS[Q][DS];
  __shared__ __align__(16) float Msd[Q][Q + 4];
  __shared__ __align__(16) float xs[Q][Q + 4];
  __shared__ __align__(16) unsigned short rawS[Q + 3][Q];   // 67 x 64 bf16 raw x
  const size_t rowb = (size_t)b * L_ + (size_t)c * Q;

  if (t < Q) dtS[t] = dt[(rowb + t) * NH + h];
  __syncthreads();
  if (t == 0) {                    // serial cumsum (64 adds)
    float A = -expf(A_log[h]);
    float s = 0.f;
    for (int q = 0; q < Q; ++q) { s += dtS[q] * A; csS[q] = s; }
  }
  __syncthreads();
  if (t < Q) {
    ddS[t] = expf(csS[Q - 1] - csS[t]) * dtS[t];    // decay_states * dt
    cs_out[(((size_t)b * NCH + c) * NH + h) * Q + t] = csS[t];
  }
  for (int i = t; i < Q * DS; i += 256) {
    int q = i >> 4, n = i & 15;
    BsS[q][n] = bc[(rowb + q) * 32 + n];
    CsS[q][n] = bc[(rowb + q) * 32 + 16 + n];
  }
  __syncthreads();
  const float Dh = Dp[h];
  // Msd[q][s] = L[q,s]*dot(C_q,B_s)*dt[s]  (+ D[h] on the diagonal, absorbing D*x)
  for (int i = t; i < Q * Q; i += 256) {
    int q = i >> 6, s = i & 63;
    float v = 0.f;
    if (s <= q) {
      float d = 0.f;
      #pragma unroll
      for (int n = 0; n < DS; ++n) d += CsS[q][n] * BsS[s][n];
      v = expf(csS[q] - csS[s]) * d * dtS[s];
      if (s == q) v += Dh;
    }
    Msd[q][s] = v;
  }
  __syncthreads();

  const int qg = t >> 4, pg = t & 15;   // Y_diag: 4q x 4p per thread
  const int ps = t & 63, n4 = t >> 6;   // states: 1p x 4n per thread
  const int pch = t & 63, qb0 = t >> 6; // conv: channel + q-phase

  for (int pt = 0; pt < 4; ++pt) {
    const int col0 = DI + h * HP + pt * Q;   // zx column of this x-tile
    // stage raw rows rowb-3 .. rowb+63 (seq-start guarded)
    for (int v = t; v < 67 * 8; v += 256) {
      int i = v >> 3, p0 = (v & 7) * 8;
      int lg = c * Q - 3 + i;
      uint4 val = make_uint4(0, 0, 0, 0);
      if (lg >= 0)
        val = *(const uint4*)(zx + ((size_t)b * L_ + lg) * DP + col0 + p0);
      *(uint4*)&rawS[i][p0] = val;
    }
    __syncthreads();
    // xs[q][p] = silu(conv4(raw))   (x, not yet * dt)
    {
      const int cc = h * HP + pt * Q + pch;
      const float w0 = cw[cc * 4 + 0], w1 = cw[cc * 4 + 1];
      const float w2 = cw[cc * 4 + 2], w3 = cw[cc * 4 + 3];
      const float bias = cb[cc];
      #pragma unroll
      for (int i2 = 0; i2 < 16; ++i2) {
        int q = qb0 + 4 * i2;
        float a = bias + bf2f(rawS[q][pch]) * w0 + bf2f(rawS[q + 1][pch]) * w1
                       + bf2f(rawS[q + 2][pch]) * w2 + bf2f(rawS[q + 3][pch]) * w3;
        xs[q][pch] = silu_f(a);
      }
    }
    __syncthreads();
    // states[p,n] = sum_q B[q,n] * (decay*dt)[q] * x[q,p]
    {
      float a0 = 0, a1 = 0, a2 = 0, a3 = 0;
      for (int q = 0; q < Q; ++q) {
        float w = xs[q][ps] * ddS[q];
        a0 += w * BsS[q][n4 * 4 + 0];
        a1 += w * BsS[q][n4 * 4 + 1];
        a2 += w * BsS[q][n4 * 4 + 2];
        a3 += w * BsS[q][n4 * 4 + 3];
      }
      size_t sb = ((((size_t)b * NCH + c) * NH + h) * HP + pt * Q + ps) * DS + n4 * 4;
      *(float4*)(states + sb) = make_float4(a0, a1, a2, a3);
    }
    // Y_diag + D*x = Msd @ xs   (s-blocked b128 LDS reads), store bf16
    {
      float acc[4][4] = {};
      for (int s0 = 0; s0 < Q; s0 += 4) {
        float xr[4][4], mr[4][4];
        #pragma unroll
        for (int k = 0; k < 4; ++k) *(float4*)xr[k] = *(const float4*)&xs[s0 + k][pg * 4];
        #pragma unroll
        for (int i = 0; i < 4; ++i) *(float4*)mr[i] = *(const float4*)&Msd[qg * 4 + i][s0];
        #pragma unroll
        for (int i = 0; i < 4; ++i)
          #pragma unroll
          for (int k = 0; k < 4; ++k)
            #pragma unroll
            for (int j = 0; j < 4; ++j)
              acc[i][j] += mr[i][k] * xr[k][j];
      }
      #pragma unroll
      for (int i = 0; i < 4; ++i) {
        size_t row = rowb + qg * 4 + i;
        ushort4 o;
        o.x = f2bf(acc[i][0]); o.y = f2bf(acc[i][1]);
        o.z = f2bf(acc[i][2]); o.w = f2bf(acc[i][3]);
        *(ushort4*)(yb + row * DI + h * HP + pt * Q + pg * 4) = o;
      }
    }
    __syncthreads();   // protect rawS/xs before next tile
  }
}

// ---------------- sequential inter-chunk scan (IN-PLACE: states -> prev) ----------------
__global__ __launch_bounds__(256)
void scan_kernel(float* __restrict__ states, const float* __restrict__ cs) {
  const int pn = blockIdx.x * 256 + threadIdx.x;   // 0..4095
  const int h = blockIdx.y, b = blockIdx.z;
  const size_t cstride = (size_t)NH * HP * DS;
  const size_t base = ((size_t)b * NCH * NH + h) * (size_t)(HP * DS) + pn;
  float carry = 0.f;
  for (int c = 0; c < NCH; ++c) {
    float dec = expf(cs[(((size_t)b * NCH + c) * NH + h) * Q + (Q - 1)]);
    float st = states[base + (size_t)c * cstride];
    states[base + (size_t)c * cstride] = carry;    // becomes prev
    carry = dec * carry + st;
  }
}

// ---------------- Y_off accumulation into bf16 y ----------------
__global__ __launch_bounds__(256)
void yoff_kernel(const float* __restrict__ bc, const float* __restrict__ cs,
                 const float* __restrict__ prev, unsigned short* __restrict__ yb) {
  const int c = blockIdx.x, h = blockIdx.y, b = blockIdx.z;
  const int t = threadIdx.x;                       // = p (0..255)
  __shared__ __align__(16) float CsS[Q][DS];
  __shared__ float ecs[Q];
  const size_t rowb = (size_t)b * L_ + (size_t)c * Q;
  const size_t pb = (((size_t)b * NCH + c) * NH + h) * (size_t)(HP * DS);
  for (int i = t; i < Q * DS; i += 256) {
    int q = i >> 4, n = i & 15;
    CsS[q][n] = bc[(rowb + q) * 32 + 16 + n];
  }
  if (t < Q) ecs[t] = expf(cs[(((size_t)b * NCH + c) * NH + h) * Q + t]);
  float pv[16];
  #pragma unroll
  for (int k = 0; k < 4; ++k)
    *(float4*)&pv[k * 4] = *(const float4*)(prev + pb + (size_t)t * DS + k * 4);
  __syncthreads();
  for (int q = 0; q < Q; ++q) {
    float acc = 0.f;
    #pragma unroll
    for (int n = 0; n < DS; ++n) acc += CsS[q][n] * pv[n];
    const size_t idx = (rowb + q) * DI + h * HP + t;
    yb[idx] = f2bf(bf2f(yb[idx]) + ecs[q] * acc);
  }
}

// ---------------- gate with silu(z) + RMS norm (in place on bf16 y) ----------------
__global__ __launch_bounds__(256)
void gatenorm_kernel(const unsigned short* __restrict__ zx, const float* __restrict__ norm_w,
                     unsigned short* __restrict__ yb) {
  const size_t row = blockIdx.x;
  const int t = threadIdx.x;
  const unsigned short* zrow = zx + row * DP;     // z = first DI cols
  unsigned short* yrow = yb + row * DI;
  const int d0 = t * 8;
  uint4 yv = *(const uint4*)(yrow + d0);
  uint4 zv = *(const uint4*)(zrow + d0);
  const unsigned short* ys = (const unsigned short*)&yv;
  const unsigned short* zs = (const unsigned short*)&zv;
  float v[8];
  float ss = 0.f;
  #pragma unroll
  for (int j = 0; j < 8; ++j) {
    float val = bf2f(ys[j]) * silu_f(bf2f(zs[j]));
    v[j] = val;
    ss += val * val;
  }
  #pragma unroll
  for (int off = 32; off > 0; off >>= 1) ss += __shfl_down(ss, off);
  __shared__ float red[4];
  if ((t & 63) == 0) red[t >> 6] = ss;
  __syncthreads();
  float tot = red[0] + red[1] + red[2] + red[3];
  float scale = rsqrtf(tot / (float)DI + 1e-5f);
  ushort4 o[2];
  unsigned short* op = (unsigned short*)o;
  #pragma unroll
  for (int j = 0; j < 8; ++j) op[j] = f2bf(v[j] * scale * norm_w[d0 + j]);
  *(uint4*)(yrow + d0) = *(uint4*)o;
}

// ---------------- launch ----------------
extern "C" void kernel_launch(void* const* d_in, const int* in_sizes, int n_in,
                              void* d_out, int out_size, void* d_ws, size_t ws_size,
                              hipStream_t stream) {
  const float* u       = (const float*)d_in[0];
  const float* W_in    = (const float*)d_in[1];
  const float* conv_w  = (const float*)d_in[2];
  const float* conv_b  = (const float*)d_in[3];
  const float* dt_bias = (const float*)d_in[4];
  const float* A_log   = (const float*)d_in[5];
  const float* Dp      = (const float*)d_in[6];
  const float* norm_w  = (const float*)d_in[7];
  const float* W_out   = (const float*)d_in[8];
  float* out = (float*)d_out;
  char* w = (char*)d_ws;

  unsigned short* zx = (unsigned short*)(w + OFFB_ZX);
  float* bcb         = (float*)(w + OFFB_BC);
  float* dtb         = (float*)(w + OFFB_DT);
  float* csb         = (float*)(w + OFFB_CS);
  float* stb         = (float*)(w + OFFB_ST);
  unsigned short* yb = (unsigned short*)(w + OFFB_Y);

  // 1) zxbcdt = u @ W_in  -> bf16   (16384 x 4136 x 1024)
  gemm_k<float, unsigned short><<<dim3((DP + 127) / 128, NR / 128), 256, 0, stream>>>(
      u, W_in, zx, NR, DP, DM);
  // 2) conv + silu for the 32 B/C channels (x-conv is fused into chunk_kernel)
  convbc_kernel<<<(NR * 32) / 256, 256, 0, stream>>>(zx, conv_w, conv_b, bcb);
  // 3) dt = softplus(raw + bias)
  dt_kernel<<<(NR * NH) / 256, 256, 0, stream>>>(zx, dt_bias, dtb);
  // 4) per-chunk: cumsum + x-conv + Y_diag(+Dx) + states
  chunk_kernel<<<dim3(NCH, NH, B_), 256, 0, stream>>>(zx, bcb, dtb, A_log, conv_w,
                                                      conv_b, Dp, csb, stb, yb);
  // 5) inter-chunk scan (in place: states -> prev)
  scan_kernel<<<dim3((HP * DS) / 256, NH, B_), 256, 0, stream>>>(stb, csb);
  // 6) Y_off accumulate
  yoff_kernel<<<dim3(NCH, NH, B_), 256, 0, stream>>>(bcb, csb, stb, yb);
  // 7) gate + RMS norm (in place)
  gatenorm_kernel<<<NR, 256, 0, stream>>>(zx, norm_w, yb);
  // 8) out = y @ W_out   (16384 x 1024 x 2048), bf16 A
  gemm_k<unsigned short, float><<<dim3(DM / 128, NR / 128), 256, 0, stream>>>(
      yb, W_out, out, NR, DM, DI);
}

// Round 3
// 692.375 us; speedup vs baseline: 3.9377x; 3.9377x over previous
//
#include <hip/hip_runtime.h>
#include <cstddef>
#include <cstdint>
#include <type_traits>

// ---------------- problem constants ----------------
constexpr int DM = 1024;      // D_MODEL
constexpr int DI = 2048;      // D_INNER
constexpr int DS = 16;        // D_STATE
constexpr int NH = 8;         // NHEADS
constexpr int CD = 2080;      // CONV_DIM
constexpr int DP = 4136;      // D_IN_PROJ
constexpr int DPT = 4224;     // DP padded to 33*128 (W_in^T rows)
constexpr int Q  = 64;        // CHUNK
constexpr int B_ = 4;         // BATCH
constexpr int L_ = 4096;      // SEQLEN
constexpr int NCH = 64;       // chunks per sequence
constexpr int HP = 256;       // HEADDIM
constexpr int NR = B_ * L_;   // 16384 rows

// ---------------- workspace layout (BYTE offsets, ~243.6 MB) ----------------
constexpr size_t AL(size_t x) { return (x + 255) & ~(size_t)255; }
constexpr size_t OFFB_ZX = 0;                                   // zxbcdt bf16 (NR x DP)
constexpr size_t OFFB_BC = AL(OFFB_ZX + (size_t)NR * DP * 2);   // conv'd B,C fp32 (NR x 32)
constexpr size_t OFFB_DT = AL(OFFB_BC + (size_t)NR * 32 * 4);   // dt fp32 (NR x NH)
constexpr size_t OFFB_CS = AL(OFFB_DT + (size_t)NR * NH * 4);   // cumsum fp32
constexpr size_t OFFB_ST = AL(OFFB_CS + (size_t)B_ * NCH * NH * Q * 4); // states fp32 33.55MB (aliases u_bf16)
constexpr size_t OFFB_Y  = AL(OFFB_ST + (size_t)B_ * NCH * NH * HP * DS * 4); // y bf16 67.1MB (aliases W_in^T bf16)
constexpr size_t OFFB_WO = AL(OFFB_Y + (size_t)NR * DI * 2);    // W_out^T bf16 (1024 x 2048)
// end = OFFB_WO + 1024*2048*2  ~= 243.6 MB

__device__ __forceinline__ float silu_f(float x) { return x / (1.f + expf(-x)); }
__device__ __forceinline__ float bf2f(unsigned short v) {
  unsigned int u = ((unsigned int)v) << 16;
  return __builtin_bit_cast(float, u);
}
__device__ __forceinline__ unsigned short f2bf(float f) {
  unsigned int u = __builtin_bit_cast(unsigned int, f);
  u += 0x7FFFu + ((u >> 16) & 1u);   // round-to-nearest-even
  return (unsigned short)(u >> 16);
}

typedef __attribute__((ext_vector_type(8))) short bf16x8;   // 8 bf16 = 4 VGPRs
typedef __attribute__((ext_vector_type(4))) float f32x4;

// ================= MFMA bf16 GEMM (m97 structure) =================
// C[M,N] = A[M,K] @ B^T[N,K]^T.  A,Bt bf16 row-major; 128x128 tile, BK=64.
// 256 threads = 4 waves in 2x2; each wave 64x64 via 4x4 grid of 16x16x32 MFMA.
// M%128==0, K%64==0, Bt has >= gridDim.x*128 rows (padded); C store guarded by N.
template<bool OUT_BF16>
__global__ __launch_bounds__(256)
void gemm_mfma(const unsigned short* __restrict__ A, const unsigned short* __restrict__ Bt,
               void* __restrict__ Cout, int M, int N, int K, int ldc) {
  __shared__ unsigned short As[128 * 64];   // [m][k] row-major, 16 KB
  __shared__ unsigned short Bs[128 * 64];   // [n][k] row-major, 16 KB
  const int t = threadIdx.x;
  const int w = t >> 6, l = t & 63;
  const int quad = l >> 4, lan = l & 15;
  const int wm = w >> 1, wn = w & 1;
  const int row0 = blockIdx.y * 128, col0 = blockIdx.x * 128;

  f32x4 acc[4][4];
  #pragma unroll
  for (int i = 0; i < 4; ++i)
    #pragma unroll
    for (int j = 0; j < 4; ++j)
      acc[i][j] = (f32x4)(0.0f);

  for (int k0 = 0; k0 < K; k0 += 64) {
    __syncthreads();   // previous iter's LDS readers done before overwrite
    // ---- stage A tile: 1024 x 16B chunks; lds dest = wave-uniform base + lane*16 ----
    #pragma unroll
    for (int i = 0; i < 4; ++i) {
      const int jc = i * 256 + w * 64 + l;          // chunk index (lane-contiguous)
      const int m = jc >> 3, c8 = (jc & 7) << 3;
      const unsigned short* gp = A + (size_t)(row0 + m) * K + k0 + c8;
      unsigned short* lp = &As[(size_t)(i * 256 + w * 64) * 8];
      __builtin_amdgcn_global_load_lds((const __attribute__((address_space(1))) void*)gp,
                                       (__attribute__((address_space(3))) void*)lp, 16, 0, 0);
    }
    // ---- stage B tile ----
    #pragma unroll
    for (int i = 0; i < 4; ++i) {
      const int jc = i * 256 + w * 64 + l;
      const int n = jc >> 3, c8 = (jc & 7) << 3;
      const unsigned short* gp = Bt + (size_t)(col0 + n) * K + k0 + c8;
      unsigned short* lp = &Bs[(size_t)(i * 256 + w * 64) * 8];
      __builtin_amdgcn_global_load_lds((const __attribute__((address_space(1))) void*)gp,
                                       (__attribute__((address_space(3))) void*)lp, 16, 0, 0);
    }
    __syncthreads();   // compiler emits vmcnt(0) drain here (known m97 cost)
    // ---- 32 MFMA per k-block ----
    #pragma unroll
    for (int kk = 0; kk < 64; kk += 32) {
      bf16x8 af[4], bf[4];
      #pragma unroll
      for (int mi = 0; mi < 4; ++mi)
        af[mi] = *(const bf16x8*)&As[(wm * 64 + mi * 16 + lan) * 64 + quad * 8 + kk];
      #pragma unroll
      for (int ni = 0; ni < 4; ++ni)
        bf[ni] = *(const bf16x8*)&Bs[(wn * 64 + ni * 16 + lan) * 64 + quad * 8 + kk];
      #pragma unroll
      for (int mi = 0; mi < 4; ++mi)
        #pragma unroll
        for (int ni = 0; ni < 4; ++ni)
          acc[mi][ni] = __builtin_amdgcn_mfma_f32_16x16x32_bf16(af[mi], bf[ni], acc[mi][ni], 0, 0, 0);
    }
  }
  // ---- epilogue: C/D layout col=lane&15, row=quad*4+reg ----
  #pragma unroll
  for (int mi = 0; mi < 4; ++mi) {
    const size_t rb = row0 + wm * 64 + mi * 16 + quad * 4;
    #pragma unroll
    for (int ni = 0; ni < 4; ++ni) {
      const int colb = col0 + wn * 64 + ni * 16 + lan;
      if (colb < N) {
        if constexpr (OUT_BF16) {
          unsigned short* C = (unsigned short*)Cout;
          #pragma unroll
          for (int r = 0; r < 4; ++r)
            C[(rb + r) * (size_t)ldc + colb] = f2bf(acc[mi][ni][r]);
        } else {
          float* C = (float*)Cout;
          #pragma unroll
          for (int r = 0; r < 4; ++r)
            C[(rb + r) * (size_t)ldc + colb] = acc[mi][ni][r];
        }
      }
    }
  }
}

// ---------------- fp32 -> bf16 elementwise convert ----------------
__global__ __launch_bounds__(256)
void cvt_bf16(const float* __restrict__ src, unsigned short* __restrict__ dst, size_t n4) {
  const size_t i = ((size_t)blockIdx.x * 256 + threadIdx.x) * 4;
  if (i < n4 * 4) {
    float4 v = *(const float4*)(src + i);
    ushort4 o;
    o.x = f2bf(v.x); o.y = f2bf(v.y); o.z = f2bf(v.z); o.w = f2bf(v.w);
    *(ushort4*)(dst + i) = o;
  }
}

// ---------------- fp32 [R][C] -> bf16 transposed [Cpad][R], zero-fill c>=Cvalid ----------------
__global__ __launch_bounds__(256)
void transpose_cvt(const float* __restrict__ src, unsigned short* __restrict__ dst,
                   int R, int C, int Cvalid) {
  __shared__ float T[64][65];
  const int t = threadIdx.x;
  const int n0 = blockIdx.x * 64, k0 = blockIdx.y * 64;
  #pragma unroll
  for (int i = 0; i < 4; ++i) {
    int f = t + i * 256;              // [0,1024): 64 rows x 16 float4
    int r = f >> 4, c4 = (f & 15) << 2;
    int n = n0 + c4;
    float4 v = make_float4(0.f, 0.f, 0.f, 0.f);
    if (n + 3 < Cvalid) {
      v = *(const float4*)(src + (size_t)(k0 + r) * C + n);
    } else {
      if (n + 0 < Cvalid) v.x = src[(size_t)(k0 + r) * C + n + 0];
      if (n + 1 < Cvalid) v.y = src[(size_t)(k0 + r) * C + n + 1];
      if (n + 2 < Cvalid) v.z = src[(size_t)(k0 + r) * C + n + 2];
      if (n + 3 < Cvalid) v.w = src[(size_t)(k0 + r) * C + n + 3];
    }
    T[r][c4 + 0] = v.x; T[r][c4 + 1] = v.y; T[r][c4 + 2] = v.z; T[r][c4 + 3] = v.w;
  }
  __syncthreads();
  #pragma unroll
  for (int i = 0; i < 4; ++i) {
    int f = t + i * 256;
    int c = f >> 4, r4 = (f & 15) << 2;
    ushort4 o;
    o.x = f2bf(T[r4 + 0][c]); o.y = f2bf(T[r4 + 1][c]);
    o.z = f2bf(T[r4 + 2][c]); o.w = f2bf(T[r4 + 3][c]);
    *(ushort4*)(dst + (size_t)(n0 + c) * R + k0 + r4) = o;
  }
}

// ---------------- conv+SiLU for the 32 B/C channels only ----------------
__global__ __launch_bounds__(256)
void convbc_kernel(const unsigned short* __restrict__ zx, const float* __restrict__ cw,
                   const float* __restrict__ cb, float* __restrict__ bc) {
  const int idx = blockIdx.x * 256 + threadIdx.x;   // < NR*32
  const int j = idx & 31;
  const int row = idx >> 5;
  const int l = row & (L_ - 1);
  const int cc = DI + j;                            // xBC channel 2048+j
  float a = cb[cc];
  #pragma unroll
  for (int k = 0; k < 4; ++k) {
    int ll = l - 3 + k;
    if (ll >= 0)
      a += bf2f(zx[(size_t)(row - 3 + k) * DP + (DI + DI + j)]) * cw[cc * 4 + k];
  }
  bc[(size_t)row * 32 + j] = silu_f(a);
}

// ---------------- dt = softplus(raw + bias) ----------------
__global__ __launch_bounds__(256)
void dt_kernel(const unsigned short* __restrict__ zx, const float* __restrict__ dt_bias,
               float* __restrict__ dt) {
  const int i = blockIdx.x * 256 + threadIdx.x;   // < NR*NH
  const int h = i & 7;
  const size_t row = (size_t)(i >> 3);
  float x = bf2f(zx[row * DP + (DI + CD) + h]) + dt_bias[h];
  dt[i] = (x > 20.f) ? x : log1pf(expf(x));
}

// ---------------- per-(b,chunk,head): cumsum + on-the-fly x-conv + Y_diag(+Dx) + states ----------------
__global__ __launch_bounds__(256)
void chunk_kernel(const unsigned short* __restrict__ zx, const float* __restrict__ bc,
                  const float* __restrict__ dt, const float* __restrict__ A_log,
                  const float* __restrict__ cw, const float* __restrict__ cb,
                  const float* __restrict__ Dp, float* __restrict__ cs_out,
                  float* __restrict__ states, unsigned short* __restrict__ yb) {
  const int c = blockIdx.x, h = blockIdx.y, b = blockIdx.z;
  const int t = threadIdx.x;
  __shared__ float dtS[Q], csS[Q], ddS[Q];
  __shared__ __align__(16) float BsS[Q][DS], CsS[Q][DS];
  __shared__ __align__(16) float Msd[Q][Q + 4];
  __shared__ __align__(16) float xs[Q][Q + 4];
  __shared__ __align__(16) unsigned short rawS[Q + 3][Q];   // 67 x 64 bf16 raw x
  const size_t rowb = (size_t)b * L_ + (size_t)c * Q;

  if (t < Q) dtS[t] = dt[(rowb + t) * NH + h];
  __syncthreads();
  if (t == 0) {                    // serial cumsum (64 adds)
    float A = -expf(A_log[h]);
    float s = 0.f;
    for (int q = 0; q < Q; ++q) { s += dtS[q] * A; csS[q] = s; }
  }
  __syncthreads();
  if (t < Q) {
    ddS[t] = expf(csS[Q - 1] - csS[t]) * dtS[t];    // decay_states * dt
    cs_out[(((size_t)b * NCH + c) * NH + h) * Q + t] = csS[t];
  }
  for (int i = t; i < Q * DS; i += 256) {
    int q = i >> 4, n = i & 15;
    BsS[q][n] = bc[(rowb + q) * 32 + n];
    CsS[q][n] = bc[(rowb + q) * 32 + 16 + n];
  }
  __syncthreads();
  const float Dh = Dp[h];
  for (int i = t; i < Q * Q; i += 256) {
    int q = i >> 6, s = i & 63;
    float v = 0.f;
    if (s <= q) {
      float d = 0.f;
      #pragma unroll
      for (int n = 0; n < DS; ++n) d += CsS[q][n] * BsS[s][n];
      v = expf(csS[q] - csS[s]) * d * dtS[s];
      if (s == q) v += Dh;
    }
    Msd[q][s] = v;
  }
  __syncthreads();

  const int qg = t >> 4, pg = t & 15;
  const int ps = t & 63, n4 = t >> 6;
  const int pch = t & 63, qb0 = t >> 6;

  for (int pt = 0; pt < 4; ++pt) {
    const int col0 = DI + h * HP + pt * Q;
    for (int v = t; v < 67 * 8; v += 256) {
      int i = v >> 3, p0 = (v & 7) * 8;
      int lg = c * Q - 3 + i;
      uint4 val = make_uint4(0, 0, 0, 0);
      if (lg >= 0)
        val = *(const uint4*)(zx + ((size_t)b * L_ + lg) * DP + col0 + p0);
      *(uint4*)&rawS[i][p0] = val;
    }
    __syncthreads();
    {
      const int cc = h * HP + pt * Q + pch;
      const float w0 = cw[cc * 4 + 0], w1 = cw[cc * 4 + 1];
      const float w2 = cw[cc * 4 + 2], w3 = cw[cc * 4 + 3];
      const float bias = cb[cc];
      #pragma unroll
      for (int i2 = 0; i2 < 16; ++i2) {
        int q = qb0 + 4 * i2;
        float a = bias + bf2f(rawS[q][pch]) * w0 + bf2f(rawS[q + 1][pch]) * w1
                       + bf2f(rawS[q + 2][pch]) * w2 + bf2f(rawS[q + 3][pch]) * w3;
        xs[q][pch] = silu_f(a);
      }
    }
    __syncthreads();
    {
      float a0 = 0, a1 = 0, a2 = 0, a3 = 0;
      for (int q = 0; q < Q; ++q) {
        float w = xs[q][ps] * ddS[q];
        a0 += w * BsS[q][n4 * 4 + 0];
        a1 += w * BsS[q][n4 * 4 + 1];
        a2 += w * BsS[q][n4 * 4 + 2];
        a3 += w * BsS[q][n4 * 4 + 3];
      }
      size_t sb = ((((size_t)b * NCH + c) * NH + h) * HP + pt * Q + ps) * DS + n4 * 4;
      *(float4*)(states + sb) = make_float4(a0, a1, a2, a3);
    }
    {
      float acc[4][4] = {};
      for (int s0 = 0; s0 < Q; s0 += 4) {
        float xr[4][4], mr[4][4];
        #pragma unroll
        for (int k = 0; k < 4; ++k) *(float4*)xr[k] = *(const float4*)&xs[s0 + k][pg * 4];
        #pragma unroll
        for (int i = 0; i < 4; ++i) *(float4*)mr[i] = *(const float4*)&Msd[qg * 4 + i][s0];
        #pragma unroll
        for (int i = 0; i < 4; ++i)
          #pragma unroll
          for (int k = 0; k < 4; ++k)
            #pragma unroll
            for (int j = 0; j < 4; ++j)
              acc[i][j] += mr[i][k] * xr[k][j];
      }
      #pragma unroll
      for (int i = 0; i < 4; ++i) {
        size_t row = rowb + qg * 4 + i;
        ushort4 o;
        o.x = f2bf(acc[i][0]); o.y = f2bf(acc[i][1]);
        o.z = f2bf(acc[i][2]); o.w = f2bf(acc[i][3]);
        *(ushort4*)(yb + row * DI + h * HP + pt * Q + pg * 4) = o;
      }
    }
    __syncthreads();
  }
}

// ---------------- sequential inter-chunk scan (in place: states -> prev) ----------------
__global__ __launch_bounds__(256)
void scan_kernel(float* __restrict__ states, const float* __restrict__ cs) {
  const int pn = blockIdx.x * 256 + threadIdx.x;
  const int h = blockIdx.y, b = blockIdx.z;
  const size_t cstride = (size_t)NH * HP * DS;
  const size_t base = ((size_t)b * NCH * NH + h) * (size_t)(HP * DS) + pn;
  float carry = 0.f;
  for (int c = 0; c < NCH; ++c) {
    float dec = expf(cs[(((size_t)b * NCH + c) * NH + h) * Q + (Q - 1)]);
    float st = states[base + (size_t)c * cstride];
    states[base + (size_t)c * cstride] = carry;
    carry = dec * carry + st;
  }
}

// ---------------- Y_off accumulation into bf16 y ----------------
__global__ __launch_bounds__(256)
void yoff_kernel(const float* __restrict__ bc, const float* __restrict__ cs,
                 const float* __restrict__ prev, unsigned short* __restrict__ yb) {
  const int c = blockIdx.x, h = blockIdx.y, b = blockIdx.z;
  const int t = threadIdx.x;
  __shared__ __align__(16) float CsS[Q][DS];
  __shared__ float ecs[Q];
  const size_t rowb = (size_t)b * L_ + (size_t)c * Q;
  const size_t pb = (((size_t)b * NCH + c) * NH + h) * (size_t)(HP * DS);
  for (int i = t; i < Q * DS; i += 256) {
    int q = i >> 4, n = i & 15;
    CsS[q][n] = bc[(rowb + q) * 32 + 16 + n];
  }
  if (t < Q) ecs[t] = expf(cs[(((size_t)b * NCH + c) * NH + h) * Q + t]);
  float pv[16];
  #pragma unroll
  for (int k = 0; k < 4; ++k)
    *(float4*)&pv[k * 4] = *(const float4*)(prev + pb + (size_t)t * DS + k * 4);
  __syncthreads();
  for (int q = 0; q < Q; ++q) {
    float acc = 0.f;
    #pragma unroll
    for (int n = 0; n < DS; ++n) acc += CsS[q][n] * pv[n];
    const size_t idx = (rowb + q) * DI + h * HP + t;
    yb[idx] = f2bf(bf2f(yb[idx]) + ecs[q] * acc);
  }
}

// ---------------- gate with silu(z) + RMS norm (in place on bf16 y) ----------------
__global__ __launch_bounds__(256)
void gatenorm_kernel(const unsigned short* __restrict__ zx, const float* __restrict__ norm_w,
                     unsigned short* __restrict__ yb) {
  const size_t row = blockIdx.x;
  const int t = threadIdx.x;
  const unsigned short* zrow = zx + row * DP;
  unsigned short* yrow = yb + row * DI;
  const int d0 = t * 8;
  uint4 yv = *(const uint4*)(yrow + d0);
  uint4 zv = *(const uint4*)(zrow + d0);
  const unsigned short* ys = (const unsigned short*)&yv;
  const unsigned short* zs = (const unsigned short*)&zv;
  float v[8];
  float ss = 0.f;
  #pragma unroll
  for (int j = 0; j < 8; ++j) {
    float val = bf2f(ys[j]) * silu_f(bf2f(zs[j]));
    v[j] = val;
    ss += val * val;
  }
  #pragma unroll
  for (int off = 32; off > 0; off >>= 1) ss += __shfl_down(ss, off);
  __shared__ float red[4];
  if ((t & 63) == 0) red[t >> 6] = ss;
  __syncthreads();
  float tot = red[0] + red[1] + red[2] + red[3];
  float scale = rsqrtf(tot / (float)DI + 1e-5f);
  ushort4 o[2];
  unsigned short* op = (unsigned short*)o;
  #pragma unroll
  for (int j = 0; j < 8; ++j) op[j] = f2bf(v[j] * scale * norm_w[d0 + j]);
  *(uint4*)(yrow + d0) = *(uint4*)o;
}

// ---------------- launch ----------------
extern "C" void kernel_launch(void* const* d_in, const int* in_sizes, int n_in,
                              void* d_out, int out_size, void* d_ws, size_t ws_size,
                              hipStream_t stream) {
  const float* u       = (const float*)d_in[0];
  const float* W_in    = (const float*)d_in[1];
  const float* conv_w  = (const float*)d_in[2];
  const float* conv_b  = (const float*)d_in[3];
  const float* dt_bias = (const float*)d_in[4];
  const float* A_log   = (const float*)d_in[5];
  const float* Dp      = (const float*)d_in[6];
  const float* norm_w  = (const float*)d_in[7];
  const float* W_out   = (const float*)d_in[8];
  float* out = (float*)d_out;
  char* w = (char*)d_ws;

  unsigned short* zx  = (unsigned short*)(w + OFFB_ZX);
  float* bcb          = (float*)(w + OFFB_BC);
  float* dtb          = (float*)(w + OFFB_DT);
  float* csb          = (float*)(w + OFFB_CS);
  float* stb          = (float*)(w + OFFB_ST);
  unsigned short* yb  = (unsigned short*)(w + OFFB_Y);
  unsigned short* ub  = (unsigned short*)(w + OFFB_ST);  // u bf16, dead before states written
  unsigned short* wib = (unsigned short*)(w + OFFB_Y);   // W_in^T bf16, dead before yb written
  unsigned short* wob = (unsigned short*)(w + OFFB_WO);  // W_out^T bf16

  // 0a) u -> bf16 (NR x 1024)
  cvt_bf16<<<(NR * DM / 4 + 255) / 256, 256, 0, stream>>>(u, ub, (size_t)NR * DM / 4);
  // 0b) W_in [1024][4136] -> W_in^T bf16 [4224][1024], zero-padded rows
  transpose_cvt<<<dim3(DPT / 64, DM / 64), 256, 0, stream>>>(W_in, wib, DM, DP, DP);
  // 0c) W_out [2048][1024] -> W_out^T bf16 [1024][2048]
  transpose_cvt<<<dim3(DM / 64, DI / 64), 256, 0, stream>>>(W_out, wob, DI, DM, DM);
  // 1) zxbcdt = u @ W_in -> bf16  (M=16384, N=4136 (33 col-tiles), K=1024)
  gemm_mfma<true><<<dim3(DPT / 128, NR / 128), 256, 0, stream>>>(
      ub, wib, zx, NR, DP, DM, DP);
  // 2) conv + silu for B/C channels
  convbc_kernel<<<(NR * 32) / 256, 256, 0, stream>>>(zx, conv_w, conv_b, bcb);
  // 3) dt = softplus(raw + bias)
  dt_kernel<<<(NR * NH) / 256, 256, 0, stream>>>(zx, dt_bias, dtb);
  // 4) per-chunk: cumsum + x-conv + Y_diag(+Dx) + states
  chunk_kernel<<<dim3(NCH, NH, B_), 256, 0, stream>>>(zx, bcb, dtb, A_log, conv_w,
                                                      conv_b, Dp, csb, stb, yb);
  // 5) inter-chunk scan (in place)
  scan_kernel<<<dim3((HP * DS) / 256, NH, B_), 256, 0, stream>>>(stb, csb);
  // 6) Y_off accumulate
  yoff_kernel<<<dim3(NCH, NH, B_), 256, 0, stream>>>(bcb, csb, stb, yb);
  // 7) gate + RMS norm (in place)
  gatenorm_kernel<<<NR, 256, 0, stream>>>(zx, norm_w, yb);
  // 8) out = y @ W_out  (M=16384, N=1024, K=2048)
  gemm_mfma<false><<<dim3(DM / 128, NR / 128), 256, 0, stream>>>(
      yb, wob, out, NR, DM, DI, DM);
}

// Round 4
// 662.085 us; speedup vs baseline: 4.1179x; 1.0457x over previous
//
#include <hip/hip_runtime.h>
#include <cstddef>
#include <cstdint>
#include <type_traits>

// ---------------- problem constants ----------------
constexpr int DM = 1024;      // D_MODEL
constexpr int DI = 2048;      // D_INNER
constexpr int DS = 16;        // D_STATE
constexpr int NH = 8;         // NHEADS
constexpr int CD = 2080;      // CONV_DIM
constexpr int DP = 4136;      // D_IN_PROJ
constexpr int DPT = 4224;     // DP padded to 33*128 (W_in^T rows)
constexpr int Q  = 64;        // CHUNK
constexpr int B_ = 4;         // BATCH
constexpr int L_ = 4096;      // SEQLEN
constexpr int NCH = 64;       // chunks per sequence
constexpr int HP = 256;       // HEADDIM
constexpr int NR = B_ * L_;   // 16384 rows

// ---------------- workspace layout (BYTE offsets, ~243.6 MB) ----------------
constexpr size_t AL(size_t x) { return (x + 255) & ~(size_t)255; }
constexpr size_t OFFB_ZX = 0;                                   // zxbcdt bf16 (NR x DP)
constexpr size_t OFFB_BC = AL(OFFB_ZX + (size_t)NR * DP * 2);   // conv'd B,C fp32 (NR x 32)
constexpr size_t OFFB_DT = AL(OFFB_BC + (size_t)NR * 32 * 4);   // dt fp32 (NR x NH)
constexpr size_t OFFB_CS = AL(OFFB_DT + (size_t)NR * NH * 4);   // cumsum fp32
constexpr size_t OFFB_ST = AL(OFFB_CS + (size_t)B_ * NCH * NH * Q * 4); // states fp32 33.55MB (aliases u_bf16)
constexpr size_t OFFB_Y  = AL(OFFB_ST + (size_t)B_ * NCH * NH * HP * DS * 4); // y bf16 67.1MB (aliases W_in^T bf16)
constexpr size_t OFFB_WO = AL(OFFB_Y + (size_t)NR * DI * 2);    // W_out^T bf16 (1024 x 2048)
// end = OFFB_WO + 1024*2048*2  ~= 243.6 MB

__device__ __forceinline__ float silu_f(float x) { return x / (1.f + expf(-x)); }
__device__ __forceinline__ float bf2f(unsigned short v) {
  unsigned int u = ((unsigned int)v) << 16;
  return __builtin_bit_cast(float, u);
}
__device__ __forceinline__ unsigned short f2bf(float f) {
  unsigned int u = __builtin_bit_cast(unsigned int, f);
  u += 0x7FFFu + ((u >> 16) & 1u);   // round-to-nearest-even
  return (unsigned short)(u >> 16);
}

typedef __attribute__((ext_vector_type(8))) short bf16x8;   // 8 bf16 = 4 VGPRs
typedef __attribute__((ext_vector_type(4))) float f32x4;

// ================= MFMA bf16 GEMM (m97 structure + XOR bank swizzle) =================
// C[M,N] = A[M,K] @ B^T[N,K]^T.  A,Bt bf16 row-major; 128x128 tile, BK=64.
// 256 threads = 4 waves in 2x2; each wave 64x64 via 4x4 grid of 16x16x32 MFMA.
// LDS tiles store 16B chunk (m,c8) at chunk index m*8 + (c8 ^ (m&7)):
//  - staging stays lane-contiguous (global_load_lds constraint) and coalesced
//    (per-128B-row lane permutation only);
//  - fragment reads hit all 32 banks across each quad's 16 lanes (2 lanes/bank = free).
// M%128==0, K%64==0, Bt has >= gridDim.x*128 rows (padded); C store guarded by N.
template<bool OUT_BF16>
__global__ __launch_bounds__(256)
void gemm_mfma(const unsigned short* __restrict__ A, const unsigned short* __restrict__ Bt,
               void* __restrict__ Cout, int M, int N, int K, int ldc) {
  __shared__ unsigned short As[128 * 64];   // swizzled [m][c8^(m&7)] chunks, 16 KB
  __shared__ unsigned short Bs[128 * 64];
  const int t = threadIdx.x;
  const int w = t >> 6, l = t & 63;
  const int quad = l >> 4, lan = l & 15;
  const int wm = w >> 1, wn = w & 1;
  const int row0 = blockIdx.y * 128, col0 = blockIdx.x * 128;

  f32x4 acc[4][4];
  #pragma unroll
  for (int i = 0; i < 4; ++i)
    #pragma unroll
    for (int j = 0; j < 4; ++j)
      acc[i][j] = (f32x4)(0.0f);

  for (int k0 = 0; k0 < K; k0 += 64) {
    __syncthreads();   // previous iter's LDS readers done before overwrite
    // ---- stage A tile: 1024 x 16B chunks; LDS dest = wave-uniform base + lane*16 ----
    #pragma unroll
    for (int i = 0; i < 4; ++i) {
      const int jc = i * 256 + w * 64 + l;          // LDS chunk index (lane-contiguous)
      const int m = jc >> 3, c8 = jc & 7;
      const int gc8 = c8 ^ (m & 7);                 // global chunk this lane fetches
      const unsigned short* gp = A + (size_t)(row0 + m) * K + k0 + (gc8 << 3);
      unsigned short* lp = &As[(size_t)(i * 256 + w * 64) * 8];
      __builtin_amdgcn_global_load_lds((const __attribute__((address_space(1))) void*)gp,
                                       (__attribute__((address_space(3))) void*)lp, 16, 0, 0);
    }
    // ---- stage B tile ----
    #pragma unroll
    for (int i = 0; i < 4; ++i) {
      const int jc = i * 256 + w * 64 + l;
      const int n = jc >> 3, c8 = jc & 7;
      const int gc8 = c8 ^ (n & 7);
      const unsigned short* gp = Bt + (size_t)(col0 + n) * K + k0 + (gc8 << 3);
      unsigned short* lp = &Bs[(size_t)(i * 256 + w * 64) * 8];
      __builtin_amdgcn_global_load_lds((const __attribute__((address_space(1))) void*)gp,
                                       (__attribute__((address_space(3))) void*)lp, 16, 0, 0);
    }
    __syncthreads();   // compiler emits vmcnt(0) drain here (known m97 cost)
    // ---- 32 MFMA per k-block ----
    #pragma unroll
    for (int kk = 0; kk < 64; kk += 32) {
      const int kc = quad + (kk >> 3);              // chunk column 0..7 for this quad
      bf16x8 af[4], bf[4];
      #pragma unroll
      for (int mi = 0; mi < 4; ++mi) {
        const int m = wm * 64 + mi * 16 + lan;
        af[mi] = *(const bf16x8*)&As[m * 64 + ((kc ^ (m & 7)) << 3)];
      }
      #pragma unroll
      for (int ni = 0; ni < 4; ++ni) {
        const int n = wn * 64 + ni * 16 + lan;
        bf[ni] = *(const bf16x8*)&Bs[n * 64 + ((kc ^ (n & 7)) << 3)];
      }
      #pragma unroll
      for (int mi = 0; mi < 4; ++mi)
        #pragma unroll
        for (int ni = 0; ni < 4; ++ni)
          acc[mi][ni] = __builtin_amdgcn_mfma_f32_16x16x32_bf16(af[mi], bf[ni], acc[mi][ni], 0, 0, 0);
    }
  }
  // ---- epilogue: C/D layout col=lane&15, row=quad*4+reg ----
  #pragma unroll
  for (int mi = 0; mi < 4; ++mi) {
    const size_t rb = row0 + wm * 64 + mi * 16 + quad * 4;
    #pragma unroll
    for (int ni = 0; ni < 4; ++ni) {
      const int colb = col0 + wn * 64 + ni * 16 + lan;
      if (colb < N) {
        if constexpr (OUT_BF16) {
          unsigned short* C = (unsigned short*)Cout;
          #pragma unroll
          for (int r = 0; r < 4; ++r)
            C[(rb + r) * (size_t)ldc + colb] = f2bf(acc[mi][ni][r]);
        } else {
          float* C = (float*)Cout;
          #pragma unroll
          for (int r = 0; r < 4; ++r)
            C[(rb + r) * (size_t)ldc + colb] = acc[mi][ni][r];
        }
      }
    }
  }
}

// ---------------- fp32 -> bf16 elementwise convert ----------------
__global__ __launch_bounds__(256)
void cvt_bf16(const float* __restrict__ src, unsigned short* __restrict__ dst, size_t n4) {
  const size_t i = ((size_t)blockIdx.x * 256 + threadIdx.x) * 4;
  if (i < n4 * 4) {
    float4 v = *(const float4*)(src + i);
    ushort4 o;
    o.x = f2bf(v.x); o.y = f2bf(v.y); o.z = f2bf(v.z); o.w = f2bf(v.w);
    *(ushort4*)(dst + i) = o;
  }
}

// ---------------- fp32 [R][C] -> bf16 transposed [Cpad][R], zero-fill c>=Cvalid ----------------
__global__ __launch_bounds__(256)
void transpose_cvt(const float* __restrict__ src, unsigned short* __restrict__ dst,
                   int R, int C, int Cvalid) {
  __shared__ float T[64][65];
  const int t = threadIdx.x;
  const int n0 = blockIdx.x * 64, k0 = blockIdx.y * 64;
  #pragma unroll
  for (int i = 0; i < 4; ++i) {
    int f = t + i * 256;              // [0,1024): 64 rows x 16 float4
    int r = f >> 4, c4 = (f & 15) << 2;
    int n = n0 + c4;
    float4 v = make_float4(0.f, 0.f, 0.f, 0.f);
    if (n + 3 < Cvalid) {
      v = *(const float4*)(src + (size_t)(k0 + r) * C + n);
    } else {
      if (n + 0 < Cvalid) v.x = src[(size_t)(k0 + r) * C + n + 0];
      if (n + 1 < Cvalid) v.y = src[(size_t)(k0 + r) * C + n + 1];
      if (n + 2 < Cvalid) v.z = src[(size_t)(k0 + r) * C + n + 2];
      if (n + 3 < Cvalid) v.w = src[(size_t)(k0 + r) * C + n + 3];
    }
    T[r][c4 + 0] = v.x; T[r][c4 + 1] = v.y; T[r][c4 + 2] = v.z; T[r][c4 + 3] = v.w;
  }
  __syncthreads();
  #pragma unroll
  for (int i = 0; i < 4; ++i) {
    int f = t + i * 256;
    int c = f >> 4, r4 = (f & 15) << 2;
    ushort4 o;
    o.x = f2bf(T[r4 + 0][c]); o.y = f2bf(T[r4 + 1][c]);
    o.z = f2bf(T[r4 + 2][c]); o.w = f2bf(T[r4 + 3][c]);
    *(ushort4*)(dst + (size_t)(n0 + c) * R + k0 + r4) = o;
  }
}

// ---------------- conv+SiLU for the 32 B/C channels only ----------------
__global__ __launch_bounds__(256)
void convbc_kernel(const unsigned short* __restrict__ zx, const float* __restrict__ cw,
                   const float* __restrict__ cb, float* __restrict__ bc) {
  const int idx = blockIdx.x * 256 + threadIdx.x;   // < NR*32
  const int j = idx & 31;
  const int row = idx >> 5;
  const int l = row & (L_ - 1);
  const int cc = DI + j;                            // xBC channel 2048+j
  float a = cb[cc];
  #pragma unroll
  for (int k = 0; k < 4; ++k) {
    int ll = l - 3 + k;
    if (ll >= 0)
      a += bf2f(zx[(size_t)(row - 3 + k) * DP + (DI + DI + j)]) * cw[cc * 4 + k];
  }
  bc[(size_t)row * 32 + j] = silu_f(a);
}

// ---------------- dt = softplus(raw + bias) ----------------
__global__ __launch_bounds__(256)
void dt_kernel(const unsigned short* __restrict__ zx, const float* __restrict__ dt_bias,
               float* __restrict__ dt) {
  const int i = blockIdx.x * 256 + threadIdx.x;   // < NR*NH
  const int h = i & 7;
  const size_t row = (size_t)(i >> 3);
  float x = bf2f(zx[row * DP + (DI + CD) + h]) + dt_bias[h];
  dt[i] = (x > 20.f) ? x : log1pf(expf(x));
}

// ---------------- per-(b,chunk,head): cumsum + on-the-fly x-conv + Y_diag(+Dx) + states ----------------
__global__ __launch_bounds__(256)
void chunk_kernel(const unsigned short* __restrict__ zx, const float* __restrict__ bc,
                  const float* __restrict__ dt, const float* __restrict__ A_log,
                  const float* __restrict__ cw, const float* __restrict__ cb,
                  const float* __restrict__ Dp, float* __restrict__ cs_out,
                  float* __restrict__ states, unsigned short* __restrict__ yb) {
  const int c = blockIdx.x, h = blockIdx.y, b = blockIdx.z;
  const int t = threadIdx.x;
  __shared__ float dtS[Q], csS[Q], ddS[Q];
  __shared__ __align__(16) float BsS[Q][DS], CsS[Q][DS];
  __shared__ __align__(16) float Msd[Q][Q + 4];
  __shared__ __align__(16) float xs[Q][Q + 4];
  __shared__ __align__(16) unsigned short rawS[Q + 3][Q];   // 67 x 64 bf16 raw x
  const size_t rowb = (size_t)b * L_ + (size_t)c * Q;

  if (t < Q) dtS[t] = dt[(rowb + t) * NH + h];
  __syncthreads();
  if (t == 0) {                    // serial cumsum (64 adds)
    float A = -expf(A_log[h]);
    float s = 0.f;
    for (int q = 0; q < Q; ++q) { s += dtS[q] * A; csS[q] = s; }
  }
  __syncthreads();
  if (t < Q) {
    ddS[t] = expf(csS[Q - 1] - csS[t]) * dtS[t];    // decay_states * dt
    cs_out[(((size_t)b * NCH + c) * NH + h) * Q + t] = csS[t];
  }
  for (int i = t; i < Q * DS; i += 256) {
    int q = i >> 4, n = i & 15;
    BsS[q][n] = bc[(rowb + q) * 32 + n];
    CsS[q][n] = bc[(rowb + q) * 32 + 16 + n];
  }
  __syncthreads();
  const float Dh = Dp[h];
  for (int i = t; i < Q * Q; i += 256) {
    int q = i >> 6, s = i & 63;
    float v = 0.f;
    if (s <= q) {
      float d = 0.f;
      #pragma unroll
      for (int n = 0; n < DS; ++n) d += CsS[q][n] * BsS[s][n];
      v = expf(csS[q] - csS[s]) * d * dtS[s];
      if (s == q) v += Dh;
    }
    Msd[q][s] = v;
  }
  __syncthreads();

  const int qg = t >> 4, pg = t & 15;
  const int ps = t & 63, n4 = t >> 6;
  const int pch = t & 63, qb0 = t >> 6;

  for (int pt = 0; pt < 4; ++pt) {
    const int col0 = DI + h * HP + pt * Q;
    for (int v = t; v < 67 * 8; v += 256) {
      int i = v >> 3, p0 = (v & 7) * 8;
      int lg = c * Q - 3 + i;
      uint4 val = make_uint4(0, 0, 0, 0);
      if (lg >= 0)
        val = *(const uint4*)(zx + ((size_t)b * L_ + lg) * DP + col0 + p0);
      *(uint4*)&rawS[i][p0] = val;
    }
    __syncthreads();
    {
      const int cc = h * HP + pt * Q + pch;
      const float w0 = cw[cc * 4 + 0], w1 = cw[cc * 4 + 1];
      const float w2 = cw[cc * 4 + 2], w3 = cw[cc * 4 + 3];
      const float bias = cb[cc];
      #pragma unroll
      for (int i2 = 0; i2 < 16; ++i2) {
        int q = qb0 + 4 * i2;
        float a = bias + bf2f(rawS[q][pch]) * w0 + bf2f(rawS[q + 1][pch]) * w1
                       + bf2f(rawS[q + 2][pch]) * w2 + bf2f(rawS[q + 3][pch]) * w3;
        xs[q][pch] = silu_f(a);
      }
    }
    __syncthreads();
    {
      float a0 = 0, a1 = 0, a2 = 0, a3 = 0;
      for (int q = 0; q < Q; ++q) {
        float w = xs[q][ps] * ddS[q];
        a0 += w * BsS[q][n4 * 4 + 0];
        a1 += w * BsS[q][n4 * 4 + 1];
        a2 += w * BsS[q][n4 * 4 + 2];
        a3 += w * BsS[q][n4 * 4 + 3];
      }
      size_t sb = ((((size_t)b * NCH + c) * NH + h) * HP + pt * Q + ps) * DS + n4 * 4;
      *(float4*)(states + sb) = make_float4(a0, a1, a2, a3);
    }
    {
      float acc[4][4] = {};
      for (int s0 = 0; s0 < Q; s0 += 4) {
        float xr[4][4], mr[4][4];
        #pragma unroll
        for (int k = 0; k < 4; ++k) *(float4*)xr[k] = *(const float4*)&xs[s0 + k][pg * 4];
        #pragma unroll
        for (int i = 0; i < 4; ++i) *(float4*)mr[i] = *(const float4*)&Msd[qg * 4 + i][s0];
        #pragma unroll
        for (int i = 0; i < 4; ++i)
          #pragma unroll
          for (int k = 0; k < 4; ++k)
            #pragma unroll
            for (int j = 0; j < 4; ++j)
              acc[i][j] += mr[i][k] * xr[k][j];
      }
      #pragma unroll
      for (int i = 0; i < 4; ++i) {
        size_t row = rowb + qg * 4 + i;
        ushort4 o;
        o.x = f2bf(acc[i][0]); o.y = f2bf(acc[i][1]);
        o.z = f2bf(acc[i][2]); o.w = f2bf(acc[i][3]);
        *(ushort4*)(yb + row * DI + h * HP + pt * Q + pg * 4) = o;
      }
    }
    __syncthreads();
  }
}

// ---------------- sequential inter-chunk scan (in place: states -> prev) ----------------
__global__ __launch_bounds__(256)
void scan_kernel(float* __restrict__ states, const float* __restrict__ cs) {
  const int pn = blockIdx.x * 256 + threadIdx.x;
  const int h = blockIdx.y, b = blockIdx.z;
  const size_t cstride = (size_t)NH * HP * DS;
  const size_t base = ((size_t)b * NCH * NH + h) * (size_t)(HP * DS) + pn;
  float carry = 0.f;
  for (int c = 0; c < NCH; ++c) {
    float dec = expf(cs[(((size_t)b * NCH + c) * NH + h) * Q + (Q - 1)]);
    float st = states[base + (size_t)c * cstride];
    states[base + (size_t)c * cstride] = carry;
    carry = dec * carry + st;
  }
}

// ---------------- Y_off accumulation into bf16 y ----------------
__global__ __launch_bounds__(256)
void yoff_kernel(const float* __restrict__ bc, const float* __restrict__ cs,
                 const float* __restrict__ prev, unsigned short* __restrict__ yb) {
  const int c = blockIdx.x, h = blockIdx.y, b = blockIdx.z;
  const int t = threadIdx.x;
  __shared__ __align__(16) float CsS[Q][DS];
  __shared__ float ecs[Q];
  const size_t rowb = (size_t)b * L_ + (size_t)c * Q;
  const size_t pb = (((size_t)b * NCH + c) * NH + h) * (size_t)(HP * DS);
  for (int i = t; i < Q * DS; i += 256) {
    int q = i >> 4, n = i & 15;
    CsS[q][n] = bc[(rowb + q) * 32 + 16 + n];
  }
  if (t < Q) ecs[t] = expf(cs[(((size_t)b * NCH + c) * NH + h) * Q + t]);
  float pv[16];
  #pragma unroll
  for (int k = 0; k < 4; ++k)
    *(float4*)&pv[k * 4] = *(const float4*)(prev + pb + (size_t)t * DS + k * 4);
  __syncthreads();
  for (int q = 0; q < Q; ++q) {
    float acc = 0.f;
    #pragma unroll
    for (int n = 0; n < DS; ++n) acc += CsS[q][n] * pv[n];
    const size_t idx = (rowb + q) * DI + h * HP + t;
    yb[idx] = f2bf(bf2f(yb[idx]) + ecs[q] * acc);
  }
}

// ---------------- gate with silu(z) + RMS norm (in place on bf16 y) ----------------
__global__ __launch_bounds__(256)
void gatenorm_kernel(const unsigned short* __restrict__ zx, const float* __restrict__ norm_w,
                     unsigned short* __restrict__ yb) {
  const size_t row = blockIdx.x;
  const int t = threadIdx.x;
  const unsigned short* zrow = zx + row * DP;
  unsigned short* yrow = yb + row * DI;
  const int d0 = t * 8;
  uint4 yv = *(const uint4*)(yrow + d0);
  uint4 zv = *(const uint4*)(zrow + d0);
  const unsigned short* ys = (const unsigned short*)&yv;
  const unsigned short* zs = (const unsigned short*)&zv;
  float v[8];
  float ss = 0.f;
  #pragma unroll
  for (int j = 0; j < 8; ++j) {
    float val = bf2f(ys[j]) * silu_f(bf2f(zs[j]));
    v[j] = val;
    ss += val * val;
  }
  #pragma unroll
  for (int off = 32; off > 0; off >>= 1) ss += __shfl_down(ss, off);
  __shared__ float red[4];
  if ((t & 63) == 0) red[t >> 6] = ss;
  __syncthreads();
  float tot = red[0] + red[1] + red[2] + red[3];
  float scale = rsqrtf(tot / (float)DI + 1e-5f);
  ushort4 o[2];
  unsigned short* op = (unsigned short*)o;
  #pragma unroll
  for (int j = 0; j < 8; ++j) op[j] = f2bf(v[j] * scale * norm_w[d0 + j]);
  *(uint4*)(yrow + d0) = *(uint4*)o;
}

// ---------------- launch ----------------
extern "C" void kernel_launch(void* const* d_in, const int* in_sizes, int n_in,
                              void* d_out, int out_size, void* d_ws, size_t ws_size,
                              hipStream_t stream) {
  const float* u       = (const float*)d_in[0];
  const float* W_in    = (const float*)d_in[1];
  const float* conv_w  = (const float*)d_in[2];
  const float* conv_b  = (const float*)d_in[3];
  const float* dt_bias = (const float*)d_in[4];
  const float* A_log   = (const float*)d_in[5];
  const float* Dp      = (const float*)d_in[6];
  const float* norm_w  = (const float*)d_in[7];
  const float* W_out   = (const float*)d_in[8];
  float* out = (float*)d_out;
  char* w = (char*)d_ws;

  unsigned short* zx  = (unsigned short*)(w + OFFB_ZX);
  float* bcb          = (float*)(w + OFFB_BC);
  float* dtb          = (float*)(w + OFFB_DT);
  float* csb          = (float*)(w + OFFB_CS);
  float* stb          = (float*)(w + OFFB_ST);
  unsigned short* yb  = (unsigned short*)(w + OFFB_Y);
  unsigned short* ub  = (unsigned short*)(w + OFFB_ST);  // u bf16, dead before states written
  unsigned short* wib = (unsigned short*)(w + OFFB_Y);   // W_in^T bf16, dead before yb written
  unsigned short* wob = (unsigned short*)(w + OFFB_WO);  // W_out^T bf16

  // 0a) u -> bf16 (NR x 1024)
  cvt_bf16<<<(NR * DM / 4 + 255) / 256, 256, 0, stream>>>(u, ub, (size_t)NR * DM / 4);
  // 0b) W_in [1024][4136] -> W_in^T bf16 [4224][1024], zero-padded rows
  transpose_cvt<<<dim3(DPT / 64, DM / 64), 256, 0, stream>>>(W_in, wib, DM, DP, DP);
  // 0c) W_out [2048][1024] -> W_out^T bf16 [1024][2048]
  transpose_cvt<<<dim3(DM / 64, DI / 64), 256, 0, stream>>>(W_out, wob, DI, DM, DM);
  // 1) zxbcdt = u @ W_in -> bf16  (M=16384, N=4136 (33 col-tiles), K=1024)
  gemm_mfma<true><<<dim3(DPT / 128, NR / 128), 256, 0, stream>>>(
      ub, wib, zx, NR, DP, DM, DP);
  // 2) conv + silu for B/C channels
  convbc_kernel<<<(NR * 32) / 256, 256, 0, stream>>>(zx, conv_w, conv_b, bcb);
  // 3) dt = softplus(raw + bias)
  dt_kernel<<<(NR * NH) / 256, 256, 0, stream>>>(zx, dt_bias, dtb);
  // 4) per-chunk: cumsum + x-conv + Y_diag(+Dx) + states
  chunk_kernel<<<dim3(NCH, NH, B_), 256, 0, stream>>>(zx, bcb, dtb, A_log, conv_w,
                                                      conv_b, Dp, csb, stb, yb);
  // 5) inter-chunk scan (in place)
  scan_kernel<<<dim3((HP * DS) / 256, NH, B_), 256, 0, stream>>>(stb, csb);
  // 6) Y_off accumulate
  yoff_kernel<<<dim3(NCH, NH, B_), 256, 0, stream>>>(bcb, csb, stb, yb);
  // 7) gate + RMS norm (in place)
  gatenorm_kernel<<<NR, 256, 0, stream>>>(zx, norm_w, yb);
  // 8) out = y @ W_out  (M=16384, N=1024, K=2048)
  gemm_mfma<false><<<dim3(DM / 128, NR / 128), 256, 0, stream>>>(
      yb, wob, out, NR, DM, DI, DM);
}

// Round 5
// 578.809 us; speedup vs baseline: 4.7103x; 1.1439x over previous
//
#include <hip/hip_runtime.h>
#include <cstddef>
#include <cstdint>
#include <type_traits>

// ---------------- problem constants ----------------
constexpr int DM = 1024;      // D_MODEL
constexpr int DI = 2048;      // D_INNER
constexpr int DS = 16;        // D_STATE
constexpr int NH = 8;         // NHEADS
constexpr int CD = 2080;      // CONV_DIM
constexpr int DP = 4136;      // D_IN_PROJ
constexpr int DPT = 4224;     // DP padded to 33*128 (W_in^T rows)
constexpr int Q  = 64;        // CHUNK
constexpr int B_ = 4;         // BATCH
constexpr int L_ = 4096;      // SEQLEN
constexpr int NCH = 64;       // chunks per sequence
constexpr int HP = 256;       // HEADDIM
constexpr int NR = B_ * L_;   // 16384 rows

// ---------------- workspace layout (BYTE offsets, ~243.6 MB) ----------------
constexpr size_t AL(size_t x) { return (x + 255) & ~(size_t)255; }
constexpr size_t OFFB_ZX = 0;                                   // zxbcdt bf16 (NR x DP)
constexpr size_t OFFB_BC = AL(OFFB_ZX + (size_t)NR * DP * 2);   // conv'd B,C fp32 (NR x 32)
constexpr size_t OFFB_DT = AL(OFFB_BC + (size_t)NR * 32 * 4);   // dt fp32 (NR x NH)
constexpr size_t OFFB_CS = AL(OFFB_DT + (size_t)NR * NH * 4);   // cumsum fp32
constexpr size_t OFFB_ST = AL(OFFB_CS + (size_t)B_ * NCH * NH * Q * 4); // states fp32 33.55MB (aliases u_bf16)
constexpr size_t OFFB_Y  = AL(OFFB_ST + (size_t)B_ * NCH * NH * HP * DS * 4); // y bf16 67.1MB (aliases W_in^T bf16)
constexpr size_t OFFB_WO = AL(OFFB_Y + (size_t)NR * DI * 2);    // W_out^T bf16 (1024 x 2048)
// end = OFFB_WO + 1024*2048*2  ~= 243.6 MB

__device__ __forceinline__ float silu_f(float x) { return x / (1.f + expf(-x)); }
__device__ __forceinline__ float bf2f(unsigned short v) {
  unsigned int u = ((unsigned int)v) << 16;
  return __builtin_bit_cast(float, u);
}
__device__ __forceinline__ unsigned short f2bf(float f) {
  unsigned int u = __builtin_bit_cast(unsigned int, f);
  u += 0x7FFFu + ((u >> 16) & 1u);   // round-to-nearest-even
  return (unsigned short)(u >> 16);
}

typedef __attribute__((ext_vector_type(8))) short bf16x8;   // 8 bf16 = 4 VGPRs
typedef __attribute__((ext_vector_type(4))) float f32x4;

// ================= MFMA bf16 GEMM (m97 structure + XOR bank swizzle) =================
// C[M,N] = A[M,K] @ B^T[N,K]^T.  A,Bt bf16 row-major; 128x128 tile, BK=64.
// 256 threads = 4 waves in 2x2; each wave 64x64 via 4x4 grid of 16x16x32 MFMA.
// LDS tiles store 16B chunk (m,c8) at chunk index m*8 + (c8 ^ (m&7)) -> 0 bank conflicts
// (verified R4: SQ_LDS_BANK_CONFLICT 5.19e7 -> 0).
template<bool OUT_BF16>
__global__ __launch_bounds__(256)
void gemm_mfma(const unsigned short* __restrict__ A, const unsigned short* __restrict__ Bt,
               void* __restrict__ Cout, int M, int N, int K, int ldc) {
  __shared__ unsigned short As[128 * 64];   // swizzled [m][c8^(m&7)] chunks, 16 KB
  __shared__ unsigned short Bs[128 * 64];
  const int t = threadIdx.x;
  const int w = t >> 6, l = t & 63;
  const int quad = l >> 4, lan = l & 15;
  const int wm = w >> 1, wn = w & 1;
  const int row0 = blockIdx.y * 128, col0 = blockIdx.x * 128;

  f32x4 acc[4][4];
  #pragma unroll
  for (int i = 0; i < 4; ++i)
    #pragma unroll
    for (int j = 0; j < 4; ++j)
      acc[i][j] = (f32x4)(0.0f);

  for (int k0 = 0; k0 < K; k0 += 64) {
    __syncthreads();
    #pragma unroll
    for (int i = 0; i < 4; ++i) {
      const int jc = i * 256 + w * 64 + l;
      const int m = jc >> 3, c8 = jc & 7;
      const int gc8 = c8 ^ (m & 7);
      const unsigned short* gp = A + (size_t)(row0 + m) * K + k0 + (gc8 << 3);
      unsigned short* lp = &As[(size_t)(i * 256 + w * 64) * 8];
      __builtin_amdgcn_global_load_lds((const __attribute__((address_space(1))) void*)gp,
                                       (__attribute__((address_space(3))) void*)lp, 16, 0, 0);
    }
    #pragma unroll
    for (int i = 0; i < 4; ++i) {
      const int jc = i * 256 + w * 64 + l;
      const int n = jc >> 3, c8 = jc & 7;
      const int gc8 = c8 ^ (n & 7);
      const unsigned short* gp = Bt + (size_t)(col0 + n) * K + k0 + (gc8 << 3);
      unsigned short* lp = &Bs[(size_t)(i * 256 + w * 64) * 8];
      __builtin_amdgcn_global_load_lds((const __attribute__((address_space(1))) void*)gp,
                                       (__attribute__((address_space(3))) void*)lp, 16, 0, 0);
    }
    __syncthreads();
    #pragma unroll
    for (int kk = 0; kk < 64; kk += 32) {
      const int kc = quad + (kk >> 3);
      bf16x8 af[4], bf[4];
      #pragma unroll
      for (int mi = 0; mi < 4; ++mi) {
        const int m = wm * 64 + mi * 16 + lan;
        af[mi] = *(const bf16x8*)&As[m * 64 + ((kc ^ (m & 7)) << 3)];
      }
      #pragma unroll
      for (int ni = 0; ni < 4; ++ni) {
        const int n = wn * 64 + ni * 16 + lan;
        bf[ni] = *(const bf16x8*)&Bs[n * 64 + ((kc ^ (n & 7)) << 3)];
      }
      #pragma unroll
      for (int mi = 0; mi < 4; ++mi)
        #pragma unroll
        for (int ni = 0; ni < 4; ++ni)
          acc[mi][ni] = __builtin_amdgcn_mfma_f32_16x16x32_bf16(af[mi], bf[ni], acc[mi][ni], 0, 0, 0);
    }
  }
  #pragma unroll
  for (int mi = 0; mi < 4; ++mi) {
    const size_t rb = row0 + wm * 64 + mi * 16 + quad * 4;
    #pragma unroll
    for (int ni = 0; ni < 4; ++ni) {
      const int colb = col0 + wn * 64 + ni * 16 + lan;
      if (colb < N) {
        if constexpr (OUT_BF16) {
          unsigned short* C = (unsigned short*)Cout;
          #pragma unroll
          for (int r = 0; r < 4; ++r)
            C[(rb + r) * (size_t)ldc + colb] = f2bf(acc[mi][ni][r]);
        } else {
          float* C = (float*)Cout;
          #pragma unroll
          for (int r = 0; r < 4; ++r)
            C[(rb + r) * (size_t)ldc + colb] = acc[mi][ni][r];
        }
      }
    }
  }
}

// ---------------- fp32 -> bf16 elementwise convert ----------------
__global__ __launch_bounds__(256)
void cvt_bf16(const float* __restrict__ src, unsigned short* __restrict__ dst, size_t n4) {
  const size_t i = ((size_t)blockIdx.x * 256 + threadIdx.x) * 4;
  if (i < n4 * 4) {
    float4 v = *(const float4*)(src + i);
    ushort4 o;
    o.x = f2bf(v.x); o.y = f2bf(v.y); o.z = f2bf(v.z); o.w = f2bf(v.w);
    *(ushort4*)(dst + i) = o;
  }
}

// ---------------- fp32 [R][C] -> bf16 transposed [Cpad][R], zero-fill c>=Cvalid ----------------
__global__ __launch_bounds__(256)
void transpose_cvt(const float* __restrict__ src, unsigned short* __restrict__ dst,
                   int R, int C, int Cvalid) {
  __shared__ float T[64][65];
  const int t = threadIdx.x;
  const int n0 = blockIdx.x * 64, k0 = blockIdx.y * 64;
  #pragma unroll
  for (int i = 0; i < 4; ++i) {
    int f = t + i * 256;
    int r = f >> 4, c4 = (f & 15) << 2;
    int n = n0 + c4;
    float4 v = make_float4(0.f, 0.f, 0.f, 0.f);
    if (n + 3 < Cvalid) {
      v = *(const float4*)(src + (size_t)(k0 + r) * C + n);
    } else {
      if (n + 0 < Cvalid) v.x = src[(size_t)(k0 + r) * C + n + 0];
      if (n + 1 < Cvalid) v.y = src[(size_t)(k0 + r) * C + n + 1];
      if (n + 2 < Cvalid) v.z = src[(size_t)(k0 + r) * C + n + 2];
      if (n + 3 < Cvalid) v.w = src[(size_t)(k0 + r) * C + n + 3];
    }
    T[r][c4 + 0] = v.x; T[r][c4 + 1] = v.y; T[r][c4 + 2] = v.z; T[r][c4 + 3] = v.w;
  }
  __syncthreads();
  #pragma unroll
  for (int i = 0; i < 4; ++i) {
    int f = t + i * 256;
    int c = f >> 4, r4 = (f & 15) << 2;
    ushort4 o;
    o.x = f2bf(T[r4 + 0][c]); o.y = f2bf(T[r4 + 1][c]);
    o.z = f2bf(T[r4 + 2][c]); o.w = f2bf(T[r4 + 3][c]);
    *(ushort4*)(dst + (size_t)(n0 + c) * R + k0 + r4) = o;
  }
}

// ---------------- conv+SiLU for the 32 B/C channels only ----------------
__global__ __launch_bounds__(256)
void convbc_kernel(const unsigned short* __restrict__ zx, const float* __restrict__ cw,
                   const float* __restrict__ cb, float* __restrict__ bc) {
  const int idx = blockIdx.x * 256 + threadIdx.x;   // < NR*32
  const int j = idx & 31;
  const int row = idx >> 5;
  const int l = row & (L_ - 1);
  const int cc = DI + j;                            // xBC channel 2048+j
  float a = cb[cc];
  #pragma unroll
  for (int k = 0; k < 4; ++k) {
    int ll = l - 3 + k;
    if (ll >= 0)
      a += bf2f(zx[(size_t)(row - 3 + k) * DP + (DI + DI + j)]) * cw[cc * 4 + k];
  }
  bc[(size_t)row * 32 + j] = silu_f(a);
}

// ---------------- dt = softplus(raw + bias) ----------------
__global__ __launch_bounds__(256)
void dt_kernel(const unsigned short* __restrict__ zx, const float* __restrict__ dt_bias,
               float* __restrict__ dt) {
  const int i = blockIdx.x * 256 + threadIdx.x;   // < NR*NH
  const int h = i & 7;
  const size_t row = (size_t)(i >> 3);
  float x = bf2f(zx[row * DP + (DI + CD) + h]) + dt_bias[h];
  dt[i] = (x > 20.f) ? x : log1pf(expf(x));
}

// ---------- per-(b,chunk,head): cumsum + x-conv + MFMA Y_diag(+Dx) + MFMA states ----------
// LDS bf16 tiles use +8-element row pad (144B stride): fragment-read start banks
// distribute 8-ways x 2 lanes like the GEMM's verified 0-conflict pattern.
// BsS padded to 17 floats: kills the old 32-way conflict in the Msd build.
__global__ __launch_bounds__(256)
void chunk_kernel(const unsigned short* __restrict__ zx, const float* __restrict__ bc,
                  const float* __restrict__ dt, const float* __restrict__ A_log,
                  const float* __restrict__ cw, const float* __restrict__ cb,
                  const float* __restrict__ Dp, float* __restrict__ cs_out,
                  float* __restrict__ states, unsigned short* __restrict__ yb) {
  const int c = blockIdx.x, h = blockIdx.y, b = blockIdx.z;
  const int t = threadIdx.x;
  const int w = t >> 6, l = t & 63;
  const int quad = l >> 4, lan = l & 15;
  __shared__ float dtS[Q], csS[Q], ddS[Q];
  __shared__ float BsS[Q][DS + 1];                  // +1 pad: conflict-free s-major reads
  __shared__ float CsS[Q][DS];                      // read broadcast (q wave-uniform)
  __shared__ __align__(16) unsigned short Msd[Q][Q + 8];   // bf16 [q][s]
  __shared__ __align__(16) unsigned short BdT[DS][Q + 8];  // bf16 [n][q] = B[q][n]*dd[q]
  __shared__ __align__(16) unsigned short xsT[Q][Q + 8];   // bf16 [p][q] per p-tile
  __shared__ __align__(16) unsigned short rawS[Q + 3][Q];  // 67 x 64 bf16 raw x
  const size_t rowb = (size_t)b * L_ + (size_t)c * Q;

  if (t < Q) dtS[t] = dt[(rowb + t) * NH + h];
  __syncthreads();
  if (t == 0) {                    // serial cumsum (64 adds)
    float A = -expf(A_log[h]);
    float s = 0.f;
    for (int q = 0; q < Q; ++q) { s += dtS[q] * A; csS[q] = s; }
  }
  __syncthreads();
  if (t < Q) {
    ddS[t] = expf(csS[Q - 1] - csS[t]) * dtS[t];    // decay_states * dt
    cs_out[(((size_t)b * NCH + c) * NH + h) * Q + t] = csS[t];
  }
  for (int i = t; i < Q * DS; i += 256) {
    int q = i >> 4, n = i & 15;
    BsS[q][n] = bc[(rowb + q) * 32 + n];
    CsS[q][n] = bc[(rowb + q) * 32 + 16 + n];
  }
  __syncthreads();
  // BdT[n][q] = B[q][n] * dd[q]   (bf16)
  for (int i = t; i < DS * Q; i += 256) {
    int n = i & 15, q = i >> 4;
    BdT[n][q] = f2bf(BsS[q][n] * ddS[q]);
  }
  // Msd[q][s] = L[q,s]*dot(C_q,B_s)*dt[s] (+D[h] on diag), bf16
  const float Dh = Dp[h];
  for (int i = t; i < Q * Q; i += 256) {
    int q = i >> 6, s = i & 63;
    float v = 0.f;
    if (s <= q) {
      float d = 0.f;
      #pragma unroll
      for (int n = 0; n < DS; ++n) d += CsS[q][n] * BsS[s][n];
      v = expf(csS[q] - csS[s]) * d * dtS[s];
      if (s == q) v += Dh;
    }
    Msd[q][s] = f2bf(v);
  }
  // (Msd/BdT visibility guaranteed by the conv barrier inside the pt loop)

  const int pch = t & 63, qb0 = t >> 6;   // conv: channel + q-phase

  for (int pt = 0; pt < 4; ++pt) {
    const int col0 = DI + h * HP + pt * Q;   // zx column of this x-tile
    // stage raw rows rowb-3 .. rowb+63 (seq-start guarded)
    for (int v = t; v < 67 * 8; v += 256) {
      int i = v >> 3, p0 = (v & 7) * 8;
      int lg = c * Q - 3 + i;
      uint4 val = make_uint4(0, 0, 0, 0);
      if (lg >= 0)
        val = *(const uint4*)(zx + ((size_t)b * L_ + lg) * DP + col0 + p0);
      *(uint4*)&rawS[i][p0] = val;
    }
    __syncthreads();
    // conv+silu -> xsT[p][q] bf16 (transposed: p rows, q cols)
    {
      const int cc = h * HP + pt * Q + pch;
      const float w0 = cw[cc * 4 + 0], w1 = cw[cc * 4 + 1];
      const float w2 = cw[cc * 4 + 2], w3 = cw[cc * 4 + 3];
      const float bias = cb[cc];
      #pragma unroll
      for (int i2 = 0; i2 < 16; ++i2) {
        int q = qb0 + 4 * i2;
        float a = bias + bf2f(rawS[q][pch]) * w0 + bf2f(rawS[q + 1][pch]) * w1
                       + bf2f(rawS[q + 2][pch]) * w2 + bf2f(rawS[q + 3][pch]) * w3;
        xsT[pch][q] = f2bf(silu_f(a));
      }
    }
    __syncthreads();
    // xfrag = xsT rows w*16+lan; doubles as states-A ([m=p][k=q]) and Y_diag-B ([n=p][k=s])
    bf16x8 xfrag[2];
    #pragma unroll
    for (int ks = 0; ks < 2; ++ks)
      xfrag[ks] = *(const bf16x8*)&xsT[w * 16 + lan][quad * 8 + ks * 32];
    // states[p][n] = sum_q xsT[p][q] * BdT[n][q]  (each wave: one 16-p tile)
    {
      f32x4 sacc = (f32x4)(0.0f);
      #pragma unroll
      for (int ks = 0; ks < 2; ++ks) {
        bf16x8 bfr = *(const bf16x8*)&BdT[lan][quad * 8 + ks * 32];
        sacc = __builtin_amdgcn_mfma_f32_16x16x32_bf16(xfrag[ks], bfr, sacc, 0, 0, 0);
      }
      const int p = w * 16 + quad * 4;   // + r
      const size_t sb = ((((size_t)b * NCH + c) * NH + h) * HP + pt * Q + p) * DS + lan;
      #pragma unroll
      for (int r = 0; r < 4; ++r)
        states[sb + (size_t)r * DS] = sacc[r];
    }
    // Y_diag[q][p] = sum_s Msd[q][s] * xsT[p][s]  (each wave: one 16-p n-tile, all q)
    {
      #pragma unroll
      for (int mi = 0; mi < 4; ++mi) {
        f32x4 yac = (f32x4)(0.0f);
        #pragma unroll
        for (int ks = 0; ks < 2; ++ks) {
          bf16x8 am = *(const bf16x8*)&Msd[mi * 16 + lan][quad * 8 + ks * 32];
          yac = __builtin_amdgcn_mfma_f32_16x16x32_bf16(am, xfrag[ks], yac, 0, 0, 0);
        }
        const int qrow = mi * 16 + quad * 4;   // + r
        const int pcol = h * HP + pt * Q + w * 16 + lan;
        #pragma unroll
        for (int r = 0; r < 4; ++r)
          yb[(rowb + qrow + r) * (size_t)DI + pcol] = f2bf(yac[r]);
      }
    }
    __syncthreads();   // protect rawS/xsT before next pt overwrites
  }
}

// ---------------- sequential inter-chunk scan (in place: states -> prev) ----------------
__global__ __launch_bounds__(256)
void scan_kernel(float* __restrict__ states, const float* __restrict__ cs) {
  const int pn = blockIdx.x * 256 + threadIdx.x;
  const int h = blockIdx.y, b = blockIdx.z;
  const size_t cstride = (size_t)NH * HP * DS;
  const size_t base = ((size_t)b * NCH * NH + h) * (size_t)(HP * DS) + pn;
  float carry = 0.f;
  for (int c = 0; c < NCH; ++c) {
    float dec = expf(cs[(((size_t)b * NCH + c) * NH + h) * Q + (Q - 1)]);
    float st = states[base + (size_t)c * cstride];
    states[base + (size_t)c * cstride] = carry;
    carry = dec * carry + st;
  }
}

// ---------------- Y_off accumulation into bf16 y ----------------
__global__ __launch_bounds__(256)
void yoff_kernel(const float* __restrict__ bc, const float* __restrict__ cs,
                 const float* __restrict__ prev, unsigned short* __restrict__ yb) {
  const int c = blockIdx.x, h = blockIdx.y, b = blockIdx.z;
  const int t = threadIdx.x;
  __shared__ __align__(16) float CsS[Q][DS];
  __shared__ float ecs[Q];
  const size_t rowb = (size_t)b * L_ + (size_t)c * Q;
  const size_t pb = (((size_t)b * NCH + c) * NH + h) * (size_t)(HP * DS);
  for (int i = t; i < Q * DS; i += 256) {
    int q = i >> 4, n = i & 15;
    CsS[q][n] = bc[(rowb + q) * 32 + 16 + n];
  }
  if (t < Q) ecs[t] = expf(cs[(((size_t)b * NCH + c) * NH + h) * Q + t]);
  float pv[16];
  #pragma unroll
  for (int k = 0; k < 4; ++k)
    *(float4*)&pv[k * 4] = *(const float4*)(prev + pb + (size_t)t * DS + k * 4);
  __syncthreads();
  for (int q = 0; q < Q; ++q) {
    float acc = 0.f;
    #pragma unroll
    for (int n = 0; n < DS; ++n) acc += CsS[q][n] * pv[n];
    const size_t idx = (rowb + q) * DI + h * HP + t;
    yb[idx] = f2bf(bf2f(yb[idx]) + ecs[q] * acc);
  }
}

// ---------------- gate with silu(z) + RMS norm (in place on bf16 y) ----------------
__global__ __launch_bounds__(256)
void gatenorm_kernel(const unsigned short* __restrict__ zx, const float* __restrict__ norm_w,
                     unsigned short* __restrict__ yb) {
  const size_t row = blockIdx.x;
  const int t = threadIdx.x;
  const unsigned short* zrow = zx + row * DP;
  unsigned short* yrow = yb + row * DI;
  const int d0 = t * 8;
  uint4 yv = *(const uint4*)(yrow + d0);
  uint4 zv = *(const uint4*)(zrow + d0);
  const unsigned short* ys = (const unsigned short*)&yv;
  const unsigned short* zs = (const unsigned short*)&zv;
  float v[8];
  float ss = 0.f;
  #pragma unroll
  for (int j = 0; j < 8; ++j) {
    float val = bf2f(ys[j]) * silu_f(bf2f(zs[j]));
    v[j] = val;
    ss += val * val;
  }
  #pragma unroll
  for (int off = 32; off > 0; off >>= 1) ss += __shfl_down(ss, off);
  __shared__ float red[4];
  if ((t & 63) == 0) red[t >> 6] = ss;
  __syncthreads();
  float tot = red[0] + red[1] + red[2] + red[3];
  float scale = rsqrtf(tot / (float)DI + 1e-5f);
  ushort4 o[2];
  unsigned short* op = (unsigned short*)o;
  #pragma unroll
  for (int j = 0; j < 8; ++j) op[j] = f2bf(v[j] * scale * norm_w[d0 + j]);
  *(uint4*)(yrow + d0) = *(uint4*)o;
}

// ---------------- launch ----------------
extern "C" void kernel_launch(void* const* d_in, const int* in_sizes, int n_in,
                              void* d_out, int out_size, void* d_ws, size_t ws_size,
                              hipStream_t stream) {
  const float* u       = (const float*)d_in[0];
  const float* W_in    = (const float*)d_in[1];
  const float* conv_w  = (const float*)d_in[2];
  const float* conv_b  = (const float*)d_in[3];
  const float* dt_bias = (const float*)d_in[4];
  const float* A_log   = (const float*)d_in[5];
  const float* Dp      = (const float*)d_in[6];
  const float* norm_w  = (const float*)d_in[7];
  const float* W_out   = (const float*)d_in[8];
  float* out = (float*)d_out;
  char* w = (char*)d_ws;

  unsigned short* zx  = (unsigned short*)(w + OFFB_ZX);
  float* bcb          = (float*)(w + OFFB_BC);
  float* dtb          = (float*)(w + OFFB_DT);
  float* csb          = (float*)(w + OFFB_CS);
  float* stb          = (float*)(w + OFFB_ST);
  unsigned short* yb  = (unsigned short*)(w + OFFB_Y);
  unsigned short* ub  = (unsigned short*)(w + OFFB_ST);  // u bf16, dead before states written
  unsigned short* wib = (unsigned short*)(w + OFFB_Y);   // W_in^T bf16, dead before yb written
  unsigned short* wob = (unsigned short*)(w + OFFB_WO);  // W_out^T bf16

  // 0a) u -> bf16 (NR x 1024)
  cvt_bf16<<<(NR * DM / 4 + 255) / 256, 256, 0, stream>>>(u, ub, (size_t)NR * DM / 4);
  // 0b) W_in [1024][4136] -> W_in^T bf16 [4224][1024], zero-padded rows
  transpose_cvt<<<dim3(DPT / 64, DM / 64), 256, 0, stream>>>(W_in, wib, DM, DP, DP);
  // 0c) W_out [2048][1024] -> W_out^T bf16 [1024][2048]
  transpose_cvt<<<dim3(DM / 64, DI / 64), 256, 0, stream>>>(W_out, wob, DI, DM, DM);
  // 1) zxbcdt = u @ W_in -> bf16  (M=16384, N=4136 (33 col-tiles), K=1024)
  gemm_mfma<true><<<dim3(DPT / 128, NR / 128), 256, 0, stream>>>(
      ub, wib, zx, NR, DP, DM, DP);
  // 2) conv + silu for B/C channels
  convbc_kernel<<<(NR * 32) / 256, 256, 0, stream>>>(zx, conv_w, conv_b, bcb);
  // 3) dt = softplus(raw + bias)
  dt_kernel<<<(NR * NH) / 256, 256, 0, stream>>>(zx, dt_bias, dtb);
  // 4) per-chunk: cumsum + x-conv + MFMA Y_diag(+Dx) + MFMA states
  chunk_kernel<<<dim3(NCH, NH, B_), 256, 0, stream>>>(zx, bcb, dtb, A_log, conv_w,
                                                      conv_b, Dp, csb, stb, yb);
  // 5) inter-chunk scan (in place)
  scan_kernel<<<dim3((HP * DS) / 256, NH, B_), 256, 0, stream>>>(stb, csb);
  // 6) Y_off accumulate
  yoff_kernel<<<dim3(NCH, NH, B_), 256, 0, stream>>>(bcb, csb, stb, yb);
  // 7) gate + RMS norm (in place)
  gatenorm_kernel<<<NR, 256, 0, stream>>>(zx, norm_w, yb);
  // 8) out = y @ W_out  (M=16384, N=1024, K=2048)
  gemm_mfma<false><<<dim3(DM / 128, NR / 128), 256, 0, stream>>>(
      yb, wob, out, NR, DM, DI, DM);
}

// Round 6
// 548.955 us; speedup vs baseline: 4.9665x; 1.0544x over previous
//
#include <hip/hip_runtime.h>
#include <cstddef>
#include <cstdint>
#include <type_traits>

// ---------------- problem constants ----------------
constexpr int DM = 1024;      // D_MODEL
constexpr int DI = 2048;      // D_INNER
constexpr int DS = 16;        // D_STATE
constexpr int NH = 8;         // NHEADS
constexpr int CD = 2080;      // CONV_DIM
constexpr int DP = 4136;      // D_IN_PROJ
constexpr int DPT = 4224;     // DP padded to 33*128 (W_in^T rows)
constexpr int Q  = 64;        // CHUNK
constexpr int B_ = 4;         // BATCH
constexpr int L_ = 4096;      // SEQLEN
constexpr int NCH = 64;       // chunks per sequence
constexpr int HP = 256;       // HEADDIM
constexpr int NR = B_ * L_;   // 16384 rows

// ---------------- workspace layout (BYTE offsets, ~243.6 MB) ----------------
constexpr size_t AL(size_t x) { return (x + 255) & ~(size_t)255; }
constexpr size_t OFFB_ZX = 0;                                   // zxbcdt bf16 (NR x DP)
constexpr size_t OFFB_BC = AL(OFFB_ZX + (size_t)NR * DP * 2);   // conv'd B,C fp32 (NR x 32)
constexpr size_t OFFB_DT = AL(OFFB_BC + (size_t)NR * 32 * 4);   // dt fp32 (NR x NH)
constexpr size_t OFFB_CS = AL(OFFB_DT + (size_t)NR * NH * 4);   // cumsum fp32
constexpr size_t OFFB_ST = AL(OFFB_CS + (size_t)B_ * NCH * NH * Q * 4); // states fp32 33.55MB (aliases u_bf16)
constexpr size_t OFFB_Y  = AL(OFFB_ST + (size_t)B_ * NCH * NH * HP * DS * 4); // y bf16 67.1MB (aliases W_in^T bf16)
constexpr size_t OFFB_WO = AL(OFFB_Y + (size_t)NR * DI * 2);    // W_out^T bf16 (1024 x 2048)

__device__ __forceinline__ float silu_f(float x) { return x / (1.f + expf(-x)); }
__device__ __forceinline__ float bf2f(unsigned short v) {
  unsigned int u = ((unsigned int)v) << 16;
  return __builtin_bit_cast(float, u);
}
__device__ __forceinline__ unsigned short f2bf(float f) {
  unsigned int u = __builtin_bit_cast(unsigned int, f);
  u += 0x7FFFu + ((u >> 16) & 1u);   // round-to-nearest-even
  return (unsigned short)(u >> 16);
}

typedef __attribute__((ext_vector_type(8))) short bf16x8;   // 8 bf16 = 4 VGPRs
typedef __attribute__((ext_vector_type(4))) float f32x4;

// ================= MFMA bf16 GEMM (m97 structure + XOR bank swizzle + XCD swizzle) ========
// C[M,N] = A[M,K] @ B^T[N,K]^T.  128x128 tile, BK=64, 4 waves.
// XCD swizzle: id%8 -> XCD; within an XCD, all col-tiles of a row-group run
// consecutively so the A row-tile stays resident in that XCD's 4MB L2.
// gridDim.y must be a multiple of 8.
template<bool OUT_BF16>
__global__ __launch_bounds__(256)
void gemm_mfma(const unsigned short* __restrict__ A, const unsigned short* __restrict__ Bt,
               void* __restrict__ Cout, int M, int N, int K, int ldc) {
  __shared__ unsigned short As[128 * 64];   // swizzled [m][c8^(m&7)] chunks, 16 KB
  __shared__ unsigned short Bs[128 * 64];
  const int t = threadIdx.x;
  const int w = t >> 6, l = t & 63;
  const int quad = l >> 4, lan = l & 15;
  const int wm = w >> 1, wn = w & 1;
  // XCD-aware remap
  const int ncol = gridDim.x;
  const int id = blockIdx.y * ncol + blockIdx.x;
  const int xcd = id & 7, slot = id >> 3;
  const int rpx = gridDim.y >> 3;                 // row-groups per XCD
  const int row_g = xcd * rpx + slot / ncol;
  const int col_g = slot - (slot / ncol) * ncol;
  const int row0 = row_g * 128, col0 = col_g * 128;

  f32x4 acc[4][4];
  #pragma unroll
  for (int i = 0; i < 4; ++i)
    #pragma unroll
    for (int j = 0; j < 4; ++j)
      acc[i][j] = (f32x4)(0.0f);

  for (int k0 = 0; k0 < K; k0 += 64) {
    __syncthreads();
    #pragma unroll
    for (int i = 0; i < 4; ++i) {
      const int jc = i * 256 + w * 64 + l;
      const int m = jc >> 3, c8 = jc & 7;
      const int gc8 = c8 ^ (m & 7);
      const unsigned short* gp = A + (size_t)(row0 + m) * K + k0 + (gc8 << 3);
      unsigned short* lp = &As[(size_t)(i * 256 + w * 64) * 8];
      __builtin_amdgcn_global_load_lds((const __attribute__((address_space(1))) void*)gp,
                                       (__attribute__((address_space(3))) void*)lp, 16, 0, 0);
    }
    #pragma unroll
    for (int i = 0; i < 4; ++i) {
      const int jc = i * 256 + w * 64 + l;
      const int n = jc >> 3, c8 = jc & 7;
      const int gc8 = c8 ^ (n & 7);
      const unsigned short* gp = Bt + (size_t)(col0 + n) * K + k0 + (gc8 << 3);
      unsigned short* lp = &Bs[(size_t)(i * 256 + w * 64) * 8];
      __builtin_amdgcn_global_load_lds((const __attribute__((address_space(1))) void*)gp,
                                       (__attribute__((address_space(3))) void*)lp, 16, 0, 0);
    }
    __syncthreads();
    #pragma unroll
    for (int kk = 0; kk < 64; kk += 32) {
      const int kc = quad + (kk >> 3);
      bf16x8 af[4], bf[4];
      #pragma unroll
      for (int mi = 0; mi < 4; ++mi) {
        const int m = wm * 64 + mi * 16 + lan;
        af[mi] = *(const bf16x8*)&As[m * 64 + ((kc ^ (m & 7)) << 3)];
      }
      #pragma unroll
      for (int ni = 0; ni < 4; ++ni) {
        const int n = wn * 64 + ni * 16 + lan;
        bf[ni] = *(const bf16x8*)&Bs[n * 64 + ((kc ^ (n & 7)) << 3)];
      }
      #pragma unroll
      for (int mi = 0; mi < 4; ++mi)
        #pragma unroll
        for (int ni = 0; ni < 4; ++ni)
          acc[mi][ni] = __builtin_amdgcn_mfma_f32_16x16x32_bf16(af[mi], bf[ni], acc[mi][ni], 0, 0, 0);
    }
  }
  #pragma unroll
  for (int mi = 0; mi < 4; ++mi) {
    const size_t rb = row0 + wm * 64 + mi * 16 + quad * 4;
    #pragma unroll
    for (int ni = 0; ni < 4; ++ni) {
      const int colb = col0 + wn * 64 + ni * 16 + lan;
      if (colb < N) {
        if constexpr (OUT_BF16) {
          unsigned short* C = (unsigned short*)Cout;
          #pragma unroll
          for (int r = 0; r < 4; ++r)
            C[(rb + r) * (size_t)ldc + colb] = f2bf(acc[mi][ni][r]);
        } else {
          float* C = (float*)Cout;
          #pragma unroll
          for (int r = 0; r < 4; ++r)
            C[(rb + r) * (size_t)ldc + colb] = acc[mi][ni][r];
        }
      }
    }
  }
}

// ---------------- fp32 -> bf16 elementwise convert ----------------
__global__ __launch_bounds__(256)
void cvt_bf16(const float* __restrict__ src, unsigned short* __restrict__ dst, size_t n4) {
  const size_t i = ((size_t)blockIdx.x * 256 + threadIdx.x) * 4;
  if (i < n4 * 4) {
    float4 v = *(const float4*)(src + i);
    ushort4 o;
    o.x = f2bf(v.x); o.y = f2bf(v.y); o.z = f2bf(v.z); o.w = f2bf(v.w);
    *(ushort4*)(dst + i) = o;
  }
}

// ---------------- fp32 [R][C] -> bf16 transposed [Cpad][R], zero-fill c>=Cvalid ----------------
__global__ __launch_bounds__(256)
void transpose_cvt(const float* __restrict__ src, unsigned short* __restrict__ dst,
                   int R, int C, int Cvalid) {
  __shared__ float T[64][65];
  const int t = threadIdx.x;
  const int n0 = blockIdx.x * 64, k0 = blockIdx.y * 64;
  #pragma unroll
  for (int i = 0; i < 4; ++i) {
    int f = t + i * 256;
    int r = f >> 4, c4 = (f & 15) << 2;
    int n = n0 + c4;
    float4 v = make_float4(0.f, 0.f, 0.f, 0.f);
    if (n + 3 < Cvalid) {
      v = *(const float4*)(src + (size_t)(k0 + r) * C + n);
    } else {
      if (n + 0 < Cvalid) v.x = src[(size_t)(k0 + r) * C + n + 0];
      if (n + 1 < Cvalid) v.y = src[(size_t)(k0 + r) * C + n + 1];
      if (n + 2 < Cvalid) v.z = src[(size_t)(k0 + r) * C + n + 2];
      if (n + 3 < Cvalid) v.w = src[(size_t)(k0 + r) * C + n + 3];
    }
    T[r][c4 + 0] = v.x; T[r][c4 + 1] = v.y; T[r][c4 + 2] = v.z; T[r][c4 + 3] = v.w;
  }
  __syncthreads();
  #pragma unroll
  for (int i = 0; i < 4; ++i) {
    int f = t + i * 256;
    int c = f >> 4, r4 = (f & 15) << 2;
    ushort4 o;
    o.x = f2bf(T[r4 + 0][c]); o.y = f2bf(T[r4 + 1][c]);
    o.z = f2bf(T[r4 + 2][c]); o.w = f2bf(T[r4 + 3][c]);
    *(ushort4*)(dst + (size_t)(n0 + c) * R + k0 + r4) = o;
  }
}

// ---------------- conv+SiLU for the 32 B/C channels only ----------------
__global__ __launch_bounds__(256)
void convbc_kernel(const unsigned short* __restrict__ zx, const float* __restrict__ cw,
                   const float* __restrict__ cb, float* __restrict__ bc) {
  const int idx = blockIdx.x * 256 + threadIdx.x;   // < NR*32
  const int j = idx & 31;
  const int row = idx >> 5;
  const int l = row & (L_ - 1);
  const int cc = DI + j;                            // xBC channel 2048+j
  float a = cb[cc];
  #pragma unroll
  for (int k = 0; k < 4; ++k) {
    int ll = l - 3 + k;
    if (ll >= 0)
      a += bf2f(zx[(size_t)(row - 3 + k) * DP + (DI + DI + j)]) * cw[cc * 4 + k];
  }
  bc[(size_t)row * 32 + j] = silu_f(a);
}

// ---------------- dt = softplus(raw + bias) ----------------
__global__ __launch_bounds__(256)
void dt_kernel(const unsigned short* __restrict__ zx, const float* __restrict__ dt_bias,
               float* __restrict__ dt) {
  const int i = blockIdx.x * 256 + threadIdx.x;   // < NR*NH
  const int h = i & 7;
  const size_t row = (size_t)(i >> 3);
  float x = bf2f(zx[row * DP + (DI + CD) + h]) + dt_bias[h];
  dt[i] = (x > 20.f) ? x : log1pf(expf(x));
}

// ---------- per-(b,chunk,head): scan-cumsum + x-conv + MFMA Y_diag(+Dx) + MFMA states ----------
// R5 redesign: register-prefetched raw staging, conv writes xsT via b128 (conflict-free),
// states/Y tiles staged in LDS and stored coalesced (float4/uint4, 128B segments).
// LDS aliasing: regionA = {CsS | xsT}, regionB = {rawS | stS+ytS}; total ~38.3 KB -> 4 blocks/CU.
__global__ __launch_bounds__(256)
void chunk_kernel(const unsigned short* __restrict__ zx, const float* __restrict__ bc,
                  const float* __restrict__ dt, const float* __restrict__ A_log,
                  const float* __restrict__ cw, const float* __restrict__ cb,
                  const float* __restrict__ Dp, float* __restrict__ cs_out,
                  float* __restrict__ states, unsigned short* __restrict__ yb) {
  const int c = blockIdx.x, h = blockIdx.y, b = blockIdx.z;
  const int t = threadIdx.x;
  const int w = t >> 6, l = t & 63;
  const int quad = l >> 4, lan = l & 15;
  __shared__ float dtS[Q], csS[Q], ddS[Q];
  __shared__ float BsS[Q][DS + 1];
  __shared__ __align__(16) unsigned short Msd[Q][Q + 8];   // bf16 [q][s]
  __shared__ __align__(16) unsigned short BdT[DS][Q + 8];  // bf16 [n][q] = B[q][n]*dd[q]
  __shared__ __align__(16) char regionA[Q * (Q + 8) * 2];           // {CsS | xsT}
  __shared__ __align__(16) char regionB[Q * DS * 4 + Q * (Q + 8) * 2]; // {rawS | stS+ytS}
  float (*CsS)[DS]                 = (float(*)[DS])regionA;
  unsigned short (*xsT)[Q + 8]     = (unsigned short(*)[Q + 8])regionA;
  unsigned short (*rawS)[Q]        = (unsigned short(*)[Q])regionB;
  float (*stS)[DS]                 = (float(*)[DS])regionB;
  unsigned short (*ytS)[Q + 8]     = (unsigned short(*)[Q + 8])(regionB + Q * DS * 4);
  const size_t rowb = (size_t)b * L_ + (size_t)c * Q;

  // ---- dt load + parallel inclusive scan (wave 0) ----
  if (t < Q) {
    float dtv = dt[(rowb + t) * NH + h];
    dtS[t] = dtv;
    float s = dtv * (-expf(A_log[h]));
    #pragma unroll
    for (int off = 1; off < 64; off <<= 1) {
      float n = __shfl_up(s, off, 64);
      if (t >= off) s += n;
    }
    csS[t] = s;
    float slast = __shfl(s, 63, 64);
    ddS[t] = expf(slast - s) * dtv;          // decay_states * dt
    cs_out[(((size_t)b * NCH + c) * NH + h) * Q + t] = s;
  }
  for (int i = t; i < Q * DS; i += 256) {    // B/C loads (independent of scan)
    int q = i >> 4, n = i & 15;
    BsS[q][n] = bc[(rowb + q) * 32 + n];
    CsS[q][n] = bc[(rowb + q) * 32 + 16 + n];
  }
  __syncthreads();
  // ---- BdT + Msd (bf16) ----
  for (int i = t; i < DS * Q; i += 256) {
    int n = i & 15, q = i >> 4;
    BdT[n][q] = f2bf(BsS[q][n] * ddS[q]);
  }
  const float Dh = Dp[h];
  for (int i = t; i < Q * Q; i += 256) {
    int q = i >> 6, s = i & 63;
    float v = 0.f;
    if (s <= q) {
      float d = 0.f;
      #pragma unroll
      for (int n = 0; n < DS; ++n) d += CsS[q][n] * BsS[s][n];
      v = expf(csS[q] - csS[s]) * d * dtS[s];
      if (s == q) v += Dh;
    }
    Msd[q][s] = f2bf(v);
  }

  // ---- raw x prefetch (67 rows x 64 cols bf16 = 536 uint4 chunks) ----
  const int pch = l;                         // conv channel within tile (0..63)
  uint4 r0 = make_uint4(0, 0, 0, 0), r1 = make_uint4(0, 0, 0, 0), r2 = make_uint4(0, 0, 0, 0);
  {
    const int col0 = DI + h * HP;            // pt = 0
    const unsigned short* gb = zx + ((size_t)b * L_ + (c * Q - 3)) * DP + col0;
    if (c > 0 || t >= 24) r0 = *(const uint4*)(gb + (size_t)(t >> 3) * DP + (t & 7) * 8);
    r1 = *(const uint4*)(gb + (size_t)((t + 256) >> 3) * DP + (t & 7) * 8);
    if (t < 24) r2 = *(const uint4*)(gb + (size_t)((t + 512) >> 3) * DP + (t & 7) * 8);
  }

  for (int pt = 0; pt < 4; ++pt) {
    // B0: for pt=0 nothing pending; for pt>0, B3 of prev iter protects regionB
    uint4* rw = (uint4*)rawS;
    rw[t] = r0; rw[t + 256] = r1;
    if (t < 24) rw[t + 512] = r2;
    __syncthreads();                          // B1: rawS ready (pt=0: Msd/BdT/CsS done too)
    // ---- conv+silu -> xsT[p][q], 16 consecutive q per thread, 2x b128 writes ----
    {
      const int cc = h * HP + pt * Q + pch;
      const float w0 = cw[cc * 4 + 0], w1 = cw[cc * 4 + 1];
      const float w2 = cw[cc * 4 + 2], w3 = cw[cc * 4 + 3];
      const float bias = cb[cc];
      const int q0 = w * 16;
      unsigned short ob[16];
      #pragma unroll
      for (int i2 = 0; i2 < 16; ++i2) {
        int q = q0 + i2;
        float a = bias + bf2f(rawS[q][pch]) * w0 + bf2f(rawS[q + 1][pch]) * w1
                       + bf2f(rawS[q + 2][pch]) * w2 + bf2f(rawS[q + 3][pch]) * w3;
        ob[i2] = f2bf(silu_f(a));
      }
      *(uint4*)&xsT[pch][q0 + 0] = *(uint4*)&ob[0];
      *(uint4*)&xsT[pch][q0 + 8] = *(uint4*)&ob[8];
    }
    // ---- prefetch next pt's raw tile (hides behind MFMA phase) ----
    if (pt < 3) {
      const int col0n = DI + h * HP + (pt + 1) * Q;
      const unsigned short* gb = zx + ((size_t)b * L_ + (c * Q - 3)) * DP + col0n;
      r0 = make_uint4(0, 0, 0, 0); r2 = make_uint4(0, 0, 0, 0);
      if (c > 0 || t >= 24) r0 = *(const uint4*)(gb + (size_t)(t >> 3) * DP + (t & 7) * 8);
      r1 = *(const uint4*)(gb + (size_t)((t + 256) >> 3) * DP + (t & 7) * 8);
      if (t < 24) r2 = *(const uint4*)(gb + (size_t)((t + 512) >> 3) * DP + (t & 7) * 8);
    }
    __syncthreads();                          // B2: xsT ready, rawS consumed
    // ---- MFMA phase ----
    bf16x8 xfrag[2];
    #pragma unroll
    for (int ks = 0; ks < 2; ++ks)
      xfrag[ks] = *(const bf16x8*)&xsT[w * 16 + lan][quad * 8 + ks * 32];
    {  // states[p][n] = sum_q x[p][q] * BdT[n][q] -> stS
      f32x4 sacc = (f32x4)(0.0f);
      #pragma unroll
      for (int ks = 0; ks < 2; ++ks) {
        bf16x8 bfr = *(const bf16x8*)&BdT[lan][quad * 8 + ks * 32];
        sacc = __builtin_amdgcn_mfma_f32_16x16x32_bf16(xfrag[ks], bfr, sacc, 0, 0, 0);
      }
      #pragma unroll
      for (int r = 0; r < 4; ++r)
        stS[w * 16 + quad * 4 + r][lan] = sacc[r];
    }
    {  // Y_diag[q][p] = sum_s Msd[q][s]*x[p][s] -> ytS
      #pragma unroll
      for (int mi = 0; mi < 4; ++mi) {
        f32x4 yac = (f32x4)(0.0f);
        #pragma unroll
        for (int ks = 0; ks < 2; ++ks) {
          bf16x8 am = *(const bf16x8*)&Msd[mi * 16 + lan][quad * 8 + ks * 32];
          yac = __builtin_amdgcn_mfma_f32_16x16x32_bf16(am, xfrag[ks], yac, 0, 0, 0);
        }
        #pragma unroll
        for (int r = 0; r < 4; ++r)
          ytS[mi * 16 + quad * 4 + r][w * 16 + lan] = f2bf(yac[r]);
      }
    }
    __syncthreads();                          // B3: staging tiles complete
    // ---- coalesced global stores ----
    {  // states tile: 64p x 16n fp32, fully contiguous 4KB
      const size_t stbase = ((((size_t)b * NCH + c) * NH + h) * HP + (size_t)pt * Q) * DS;
      ((float4*)(states + stbase))[t] = ((const float4*)&stS[0][0])[t];
    }
    {  // y tile: 64 rows x 128B
      const int colbase = h * HP + pt * Q;
      #pragma unroll
      for (int pass = 0; pass < 2; ++pass) {
        int q = pass * 32 + (t >> 3), p8 = (t & 7) * 8;
        *(uint4*)(yb + (rowb + q) * (size_t)DI + colbase + p8) = *(const uint4*)&ytS[q][p8];
      }
    }
    __syncthreads();                          // B4: stS/ytS reads done before next rawS write
  }
}

// ---------------- sequential inter-chunk scan (in place: states -> prev) ----------------
__global__ __launch_bounds__(256)
void scan_kernel(float* __restrict__ states, const float* __restrict__ cs) {
  const int pn = blockIdx.x * 256 + threadIdx.x;
  const int h = blockIdx.y, b = blockIdx.z;
  const size_t cstride = (size_t)NH * HP * DS;
  const size_t base = ((size_t)b * NCH * NH + h) * (size_t)(HP * DS) + pn;
  float carry = 0.f;
  for (int c = 0; c < NCH; ++c) {
    float dec = expf(cs[(((size_t)b * NCH + c) * NH + h) * Q + (Q - 1)]);
    float st = states[base + (size_t)c * cstride];
    states[base + (size_t)c * cstride] = carry;
    carry = dec * carry + st;
  }
}

// ---------------- Y_off accumulation into bf16 y ----------------
__global__ __launch_bounds__(256)
void yoff_kernel(const float* __restrict__ bc, const float* __restrict__ cs,
                 const float* __restrict__ prev, unsigned short* __restrict__ yb) {
  const int c = blockIdx.x, h = blockIdx.y, b = blockIdx.z;
  const int t = threadIdx.x;
  __shared__ __align__(16) float CsS[Q][DS];
  __shared__ float ecs[Q];
  const size_t rowb = (size_t)b * L_ + (size_t)c * Q;
  const size_t pb = (((size_t)b * NCH + c) * NH + h) * (size_t)(HP * DS);
  for (int i = t; i < Q * DS; i += 256) {
    int q = i >> 4, n = i & 15;
    CsS[q][n] = bc[(rowb + q) * 32 + 16 + n];
  }
  if (t < Q) ecs[t] = expf(cs[(((size_t)b * NCH + c) * NH + h) * Q + t]);
  float pv[16];
  #pragma unroll
  for (int k = 0; k < 4; ++k)
    *(float4*)&pv[k * 4] = *(const float4*)(prev + pb + (size_t)t * DS + k * 4);
  __syncthreads();
  for (int q = 0; q < Q; ++q) {
    float acc = 0.f;
    #pragma unroll
    for (int n = 0; n < DS; ++n) acc += CsS[q][n] * pv[n];
    const size_t idx = (rowb + q) * DI + h * HP + t;
    yb[idx] = f2bf(bf2f(yb[idx]) + ecs[q] * acc);
  }
}

// ---------------- gate with silu(z) + RMS norm (in place on bf16 y) ----------------
__global__ __launch_bounds__(256)
void gatenorm_kernel(const unsigned short* __restrict__ zx, const float* __restrict__ norm_w,
                     unsigned short* __restrict__ yb) {
  const size_t row = blockIdx.x;
  const int t = threadIdx.x;
  const unsigned short* zrow = zx + row * DP;
  unsigned short* yrow = yb + row * DI;
  const int d0 = t * 8;
  uint4 yv = *(const uint4*)(yrow + d0);
  uint4 zv = *(const uint4*)(zrow + d0);
  const unsigned short* ys = (const unsigned short*)&yv;
  const unsigned short* zs = (const unsigned short*)&zv;
  float v[8];
  float ss = 0.f;
  #pragma unroll
  for (int j = 0; j < 8; ++j) {
    float val = bf2f(ys[j]) * silu_f(bf2f(zs[j]));
    v[j] = val;
    ss += val * val;
  }
  #pragma unroll
  for (int off = 32; off > 0; off >>= 1) ss += __shfl_down(ss, off);
  __shared__ float red[4];
  if ((t & 63) == 0) red[t >> 6] = ss;
  __syncthreads();
  float tot = red[0] + red[1] + red[2] + red[3];
  float scale = rsqrtf(tot / (float)DI + 1e-5f);
  ushort4 o[2];
  unsigned short* op = (unsigned short*)o;
  #pragma unroll
  for (int j = 0; j < 8; ++j) op[j] = f2bf(v[j] * scale * norm_w[d0 + j]);
  *(uint4*)(yrow + d0) = *(uint4*)o;
}

// ---------------- launch ----------------
extern "C" void kernel_launch(void* const* d_in, const int* in_sizes, int n_in,
                              void* d_out, int out_size, void* d_ws, size_t ws_size,
                              hipStream_t stream) {
  const float* u       = (const float*)d_in[0];
  const float* W_in    = (const float*)d_in[1];
  const float* conv_w  = (const float*)d_in[2];
  const float* conv_b  = (const float*)d_in[3];
  const float* dt_bias = (const float*)d_in[4];
  const float* A_log   = (const float*)d_in[5];
  const float* Dp      = (const float*)d_in[6];
  const float* norm_w  = (const float*)d_in[7];
  const float* W_out   = (const float*)d_in[8];
  float* out = (float*)d_out;
  char* w = (char*)d_ws;

  unsigned short* zx  = (unsigned short*)(w + OFFB_ZX);
  float* bcb          = (float*)(w + OFFB_BC);
  float* dtb          = (float*)(w + OFFB_DT);
  float* csb          = (float*)(w + OFFB_CS);
  float* stb          = (float*)(w + OFFB_ST);
  unsigned short* yb  = (unsigned short*)(w + OFFB_Y);
  unsigned short* ub  = (unsigned short*)(w + OFFB_ST);  // u bf16, dead before states written
  unsigned short* wib = (unsigned short*)(w + OFFB_Y);   // W_in^T bf16, dead before yb written
  unsigned short* wob = (unsigned short*)(w + OFFB_WO);  // W_out^T bf16

  // 0a) u -> bf16 (NR x 1024)
  cvt_bf16<<<(NR * DM / 4 + 255) / 256, 256, 0, stream>>>(u, ub, (size_t)NR * DM / 4);
  // 0b) W_in [1024][4136] -> W_in^T bf16 [4224][1024], zero-padded rows
  transpose_cvt<<<dim3(DPT / 64, DM / 64), 256, 0, stream>>>(W_in, wib, DM, DP, DP);
  // 0c) W_out [2048][1024] -> W_out^T bf16 [1024][2048]
  transpose_cvt<<<dim3(DM / 64, DI / 64), 256, 0, stream>>>(W_out, wob, DI, DM, DM);
  // 1) zxbcdt = u @ W_in -> bf16  (M=16384, N=4136 (33 col-tiles), K=1024)
  gemm_mfma<true><<<dim3(DPT / 128, NR / 128), 256, 0, stream>>>(
      ub, wib, zx, NR, DP, DM, DP);
  // 2) conv + silu for B/C channels
  convbc_kernel<<<(NR * 32) / 256, 256, 0, stream>>>(zx, conv_w, conv_b, bcb);
  // 3) dt = softplus(raw + bias)
  dt_kernel<<<(NR * NH) / 256, 256, 0, stream>>>(zx, dt_bias, dtb);
  // 4) per-chunk: cumsum + x-conv + MFMA Y_diag(+Dx) + MFMA states
  chunk_kernel<<<dim3(NCH, NH, B_), 256, 0, stream>>>(zx, bcb, dtb, A_log, conv_w,
                                                      conv_b, Dp, csb, stb, yb);
  // 5) inter-chunk scan (in place)
  scan_kernel<<<dim3((HP * DS) / 256, NH, B_), 256, 0, stream>>>(stb, csb);
  // 6) Y_off accumulate
  yoff_kernel<<<dim3(NCH, NH, B_), 256, 0, stream>>>(bcb, csb, stb, yb);
  // 7) gate + RMS norm (in place)
  gatenorm_kernel<<<NR, 256, 0, stream>>>(zx, norm_w, yb);
  // 8) out = y @ W_out  (M=16384, N=1024, K=2048)
  gemm_mfma<false><<<dim3(DM / 128, NR / 128), 256, 0, stream>>>(
      yb, wob, out, NR, DM, DI, DM);
}